// Round 1
// baseline (422.316 us; speedup 1.0000x reference)
//
#include <hip/hip_runtime.h>
#include <math.h>

// ---------------- workspace layout (floats) ----------------
#define WS_SEG_NLL    0    // 8 (per b)
#define WS_SEG_VALID  8    // 8
#define WS_INTER      16   // 104 (b*13+c)
#define WS_PSUM       120  // 104
#define WS_OHCNT      224  // 104
#define WS_GRID_BCE   328
#define WS_GRID_INTER 329
#define WS_GRID_PSUM  330
#define WS_GRID_TSUM  331
#define WS_BASE_BCE   332
#define WS_SIG_ABS    333
#define WS_SIG_CNT    334
#define WS_SIG_CORR   335
#define WS_SIG_NV     336
#define WS_MASK_FLAG  337  // 1.0 => mask stored as int32, 0.0 => uint8
#define WS_FLOATS     338

__device__ inline float wave_sum(float v) {
    #pragma unroll
    for (int o = 32; o > 0; o >>= 1) v += __shfl_down(v, o, 64);
    return v;
}

// block reduce, result broadcast to all threads. OP: 0 sum, 1 min, 2 max
template <int OP>
__device__ inline float blk_red(float v, float* sb) {
    #pragma unroll
    for (int o = 32; o > 0; o >>= 1) {
        float u = __shfl_down(v, o, 64);
        v = (OP == 0) ? (v + u) : ((OP == 1) ? fminf(v, u) : fmaxf(v, u));
    }
    __syncthreads();                     // protect sb from previous use
    if ((threadIdx.x & 63) == 0) sb[threadIdx.x >> 6] = v;
    __syncthreads();
    const int nw = blockDim.x >> 6;
    float r = sb[0];
    for (int w = 1; w < nw; w++) {
        float u = sb[w];
        r = (OP == 0) ? (r + u) : ((OP == 1) ? fminf(r, u) : fmaxf(r, u));
    }
    return r;
}

// ---------------- mask dtype detection ----------------
// numpy bool -> 1 byte/elem (random nonzero everywhere); int32 0/1 -> bytes at
// idx%4 != 0 are ALL zero. Scan first 48000 bytes (safe for both layouts).
__global__ void detect_mask_kernel(const unsigned char* __restrict__ m, float* __restrict__ ws) {
    __shared__ int s_cnt;
    if (threadIdx.x == 0) s_cnt = 0;
    __syncthreads();
    int c = 0;
    for (int i = threadIdx.x; i < 48000; i += blockDim.x)
        if ((i & 3) && m[i]) c++;
    atomicAdd(&s_cnt, c);
    __syncthreads();
    if (threadIdx.x == 0) ws[WS_MASK_FLAG] = (s_cnt == 0) ? 1.0f : 0.0f;
}

// ---------------- seg: CE(ignore=255) + dice stats ----------------
__global__ __launch_bounds__(256) void seg_kernel(const float* __restrict__ pred,
                                                  const int* __restrict__ tgt,
                                                  float* __restrict__ ws) {
    const int b = blockIdx.y;
    const int HW = 512 * 512;
    const float* predb = pred + (size_t)b * 13 * HW;
    const int* tgtb = tgt + (size_t)b * HW;

    float psum[13], inter[13], cnt13[13];
    #pragma unroll
    for (int c = 0; c < 13; c++) { psum[c] = 0.f; inter[c] = 0.f; cnt13[c] = 0.f; }
    float nll = 0.f, nval = 0.f;

    const int stride = gridDim.x * blockDim.x;
    for (int i = blockIdx.x * blockDim.x + threadIdx.x; i < HW; i += stride) {
        float x[13];
        #pragma unroll
        for (int c = 0; c < 13; c++) x[c] = predb[(size_t)c * HW + i];
        const int t = tgtb[i];
        float m = x[0];
        #pragma unroll
        for (int c = 1; c < 13; c++) m = fmaxf(m, x[c]);
        float xt = x[0];
        #pragma unroll
        for (int c = 1; c < 13; c++) xt = (c == t) ? x[c] : xt;
        float se = 0.f;
        #pragma unroll
        for (int c = 0; c < 13; c++) { x[c] = __expf(x[c] - m); se += x[c]; }
        const float inv = 1.0f / se;
        #pragma unroll
        for (int c = 0; c < 13; c++) {
            const float p = x[c] * inv;
            psum[c] += p;
            const bool sel = (c == t);
            inter[c] += sel ? p : 0.f;
            cnt13[c] += sel ? 1.f : 0.f;
        }
        const bool valid = (t != 255);
        nll  += valid ? (m + __logf(se) - xt) : 0.f;
        nval += valid ? 1.f : 0.f;
    }

    __shared__ float sred[41];
    if (threadIdx.x < 41) sred[threadIdx.x] = 0.f;
    __syncthreads();
    const bool lane0 = (threadIdx.x & 63) == 0;
    #pragma unroll
    for (int c = 0; c < 13; c++) {
        float a = wave_sum(psum[c]);  if (lane0) atomicAdd(&sred[c], a);
        float d = wave_sum(inter[c]); if (lane0) atomicAdd(&sred[13 + c], d);
        float e = wave_sum(cnt13[c]); if (lane0) atomicAdd(&sred[26 + c], e);
    }
    { float a = wave_sum(nll);  if (lane0) atomicAdd(&sred[39], a); }
    { float a = wave_sum(nval); if (lane0) atomicAdd(&sred[40], a); }
    __syncthreads();
    if (threadIdx.x < 13) {
        atomicAdd(&ws[WS_PSUM  + b * 13 + threadIdx.x], sred[threadIdx.x]);
        atomicAdd(&ws[WS_INTER + b * 13 + threadIdx.x], sred[13 + threadIdx.x]);
        atomicAdd(&ws[WS_OHCNT + b * 13 + threadIdx.x], sred[26 + threadIdx.x]);
    }
    if (threadIdx.x == 64) atomicAdd(&ws[WS_SEG_NLL + b],   sred[39]);
    if (threadIdx.x == 65) atomicAdd(&ws[WS_SEG_VALID + b], sred[40]);
}

// ---------------- grid: BCE + dice scalars ----------------
__global__ __launch_bounds__(256) void grid_kernel(const float4* __restrict__ gp,
                                                   const float4* __restrict__ gt,
                                                   float* __restrict__ ws) {
    const int N4 = 2097152 / 4;
    float bce = 0.f, inter = 0.f, ps = 0.f, ts = 0.f;
    const int stride = gridDim.x * blockDim.x;
    for (int i = blockIdx.x * blockDim.x + threadIdx.x; i < N4; i += stride) {
        const float4 p4 = gp[i];
        const float4 t4 = gt[i];
        const float pa[4] = {p4.x, p4.y, p4.z, p4.w};
        const float ta[4] = {t4.x, t4.y, t4.z, t4.w};
        #pragma unroll
        for (int k = 0; k < 4; k++) {
            const float p = pa[k], t = ta[k];
            const float pc  = fminf(fmaxf(p, 1e-12f), 1.0f);
            const float qc  = fminf(fmaxf(1.f - p, 1e-12f), 1.0f);
            const float lp  = fmaxf(__logf(pc), -100.f);
            const float l1p = fmaxf(__logf(qc), -100.f);
            bce  -= t * lp + (1.f - t) * l1p;
            inter += p * t;
            ps += p;
            ts += t;
        }
    }
    __shared__ float s4[4];
    if (threadIdx.x < 4) s4[threadIdx.x] = 0.f;
    __syncthreads();
    const bool lane0 = (threadIdx.x & 63) == 0;
    { float a = wave_sum(bce);   if (lane0) atomicAdd(&s4[0], a); }
    { float a = wave_sum(inter); if (lane0) atomicAdd(&s4[1], a); }
    { float a = wave_sum(ps);    if (lane0) atomicAdd(&s4[2], a); }
    { float a = wave_sum(ts);    if (lane0) atomicAdd(&s4[3], a); }
    __syncthreads();
    if (threadIdx.x == 0) {
        atomicAdd(&ws[WS_GRID_BCE],   s4[0]);
        atomicAdd(&ws[WS_GRID_INTER], s4[1]);
        atomicAdd(&ws[WS_GRID_PSUM],  s4[2]);
        atomicAdd(&ws[WS_GRID_TSUM],  s4[3]);
    }
}

// ---------------- baseline: bilinear(align_corners) gather + BCE ----------------
__global__ __launch_bounds__(256) void baseline_kernel(const float* __restrict__ bp,
                                                       const float* __restrict__ bt,
                                                       float* __restrict__ ws) {
    const int idx = blockIdx.x * blockDim.x + threadIdx.x; // 0..98303
    float bce = 0.f;
    {
        const int w  = idx & 31;
        const int h  = (idx >> 5) & 31;
        const int bc = idx >> 10;                 // b*12 + c
        const float* img = bt + (size_t)bc * 262144;
        const float step = 511.0f / 31.0f;
        const float yy = h * step, xx = w * step;
        int y0 = (int)floorf(yy); int y1 = min(y0 + 1, 511); const float wy = yy - y0;
        int x0 = (int)floorf(xx); int x1 = min(x0 + 1, 511); const float wx = xx - x0;
        const float v00 = img[y0 * 512 + x0], v01 = img[y0 * 512 + x1];
        const float v10 = img[y1 * 512 + x0], v11 = img[y1 * 512 + x1];
        const float r0 = v00 * (1.f - wy) + v10 * wy;
        const float r1 = v01 * (1.f - wy) + v11 * wy;
        const float t  = r0 * (1.f - wx) + r1 * wx;
        const float p  = bp[idx];
        const float pc  = fminf(fmaxf(p, 1e-12f), 1.0f);
        const float qc  = fminf(fmaxf(1.f - p, 1e-12f), 1.0f);
        const float lp  = fmaxf(__logf(pc), -100.f);
        const float l1p = fmaxf(__logf(qc), -100.f);
        bce = -(t * lp + (1.f - t) * l1p);
    }
    __shared__ float sb[4];
    const float s = blk_red<0>(bce, sb);
    if (threadIdx.x == 0) atomicAdd(&ws[WS_BASE_BCE], s);
}

// ---------------- signal: masked normalize + MAE + Pearson ----------------
__global__ __launch_bounds__(256) void signal_kernel(const float* __restrict__ sp,
                                                     const float* __restrict__ st,
                                                     const void* __restrict__ mp,
                                                     float* __restrict__ ws) {
    const int T = 5000;
    const int bl = blockIdx.x;     // 0..95
    const int b = bl / 12, l = bl % 12;
    const float* ps = sp + (size_t)(b * 12 + l) * T;          // (B,12,T)
    const float* ts_base = st + (size_t)b * T * 12 + l;       // (B,T,12)
    const bool m32 = ws[WS_MASK_FLAG] > 0.5f;
    const int* mi = (const int*)mp;
    const unsigned char* mb = (const unsigned char*)mp;
    const size_t mbase = (size_t)b * T * 12 + l;

    __shared__ float sb[4];

    float cnt = 0.f;
    float mnp = __builtin_inff(), mxp = -__builtin_inff();
    float mnt = __builtin_inff(), mxt = -__builtin_inff();
    for (int t = threadIdx.x; t < T; t += blockDim.x) {
        const bool m = m32 ? (mi[mbase + (size_t)t * 12] != 0)
                           : (mb[mbase + (size_t)t * 12] != 0);
        const float p  = ps[t];
        const float tv = ts_base[(size_t)t * 12];
        if (m) {
            cnt += 1.f;
            mnp = fminf(mnp, p);  mxp = fmaxf(mxp, p);
            mnt = fminf(mnt, tv); mxt = fmaxf(mxt, tv);
        }
    }
    cnt = blk_red<0>(cnt, sb);
    mnp = blk_red<1>(mnp, sb); mxp = blk_red<2>(mxp, sb);
    mnt = blk_red<1>(mnt, sb); mxt = blk_red<2>(mxt, sb);

    const float rngp = mxp - mnp, rngt = mxt - mnt;
    const bool okp = (cnt >= 2.f) && (rngp >= 1e-6f);
    const bool okt = (cnt >= 2.f) && (rngt >= 1e-6f);
    const float mnp_s = okp ? mnp : 0.f, rp = okp ? rngp : 1.f;
    const float mnt_s = okt ? mnt : 0.f, rt = okt ? rngt : 1.f;
    const float invp = 2.f / (rp + 1e-8f), invt = 2.f / (rt + 1e-8f);

    float S_p = 0.f, S_t = 0.f, S_pt = 0.f, S_pp = 0.f, S_tt = 0.f, S_abs = 0.f;
    for (int t = threadIdx.x; t < T; t += blockDim.x) {
        const bool m = m32 ? (mi[mbase + (size_t)t * 12] != 0)
                           : (mb[mbase + (size_t)t * 12] != 0);
        const float p  = ps[t];
        const float tv = ts_base[(size_t)t * 12];
        const float pn = (m && okp) ? ((p  - mnp_s) * invp - 1.f) : 0.f;
        const float tn = (m && okt) ? ((tv - mnt_s) * invt - 1.f) : 0.f;
        S_p += pn; S_t += tn;
        S_pt += pn * tn; S_pp += pn * pn; S_tt += tn * tn;
        S_abs += m ? fabsf(pn - tn) : 0.f;
    }
    S_p  = blk_red<0>(S_p, sb);
    S_t  = blk_red<0>(S_t, sb);
    S_pt = blk_red<0>(S_pt, sb);
    S_pp = blk_red<0>(S_pp, sb);
    S_tt = blk_red<0>(S_tt, sb);
    S_abs = blk_red<0>(S_abs, sb);

    if (threadIdx.x == 0) {
        const float cs = fmaxf(cnt, 1.f);
        const float pm = S_p / cs, tm = S_t / cs;
        const float num = S_pt - pm * S_t - tm * S_p + pm * tm * cnt;
        const float psd = sqrtf(fmaxf(S_pp - 2.f * pm * S_p + pm * pm * cnt, 0.f) + 1e-6f);
        const float tsd = sqrtf(fmaxf(S_tt - 2.f * tm * S_t + tm * tm * cnt, 0.f) + 1e-6f);
        float corr = num / (psd * tsd + 1e-6f);
        corr = fminf(fmaxf(corr, -1.f), 1.f);
        const float valid = (cnt >= 10.f) ? 1.f : 0.f;
        atomicAdd(&ws[WS_SIG_ABS],  S_abs);
        atomicAdd(&ws[WS_SIG_CNT],  cnt);
        atomicAdd(&ws[WS_SIG_CORR], corr * valid);
        atomicAdd(&ws[WS_SIG_NV],   valid);
    }
}

// ---------------- finalize (incl. theta) ----------------
__global__ void finalize_kernel(const float* __restrict__ tp, const float* __restrict__ tg,
                                const float* __restrict__ ws, float* __restrict__ out) {
    if (threadIdx.x != 0 || blockIdx.x != 0) return;
    // seg
    float nll = 0.f, nv = 0.f;
    for (int b = 0; b < 8; b++) { nll += ws[WS_SEG_NLL + b]; nv += ws[WS_SEG_VALID + b]; }
    const float ce = nll / fmaxf(nv, 1.f);
    float dsum = 0.f;
    for (int i = 0; i < 104; i++) {
        const float it = ws[WS_INTER + i], p = ws[WS_PSUM + i], oh = ws[WS_OHCNT + i];
        dsum += (2.f * it + 1e-7f) / (p + oh + 1e-7f);
    }
    const float seg = (ce + (1.f - dsum / 104.f)) * 1.0f;
    // grid
    const float bce_g = ws[WS_GRID_BCE] / 2097152.f;
    const float gd = 1.f - (2.f * ws[WS_GRID_INTER] + 1e-7f) /
                           (ws[WS_GRID_PSUM] + ws[WS_GRID_TSUM] + 1e-7f);
    const float grid = (bce_g + gd) * 0.5f;
    // baseline
    const float base = (ws[WS_BASE_BCE] / 98304.f) * 0.8f;
    // theta
    float th = 0.f;
    for (int i = 0; i < 48; i++) th += fabsf(tp[i] - tg[i]);
    th = (th / 48.f) * 0.3f;
    // signal
    const float mae = ws[WS_SIG_ABS] / (ws[WS_SIG_CNT] + 1e-7f);
    const float nvs = ws[WS_SIG_NV];
    const float pear = (nvs > 0.f) ? (1.f - ws[WS_SIG_CORR] / fmaxf(nvs, 1.f)) : 1.f;
    const float sig = (mae + pear) * 2.0f;

    const float total = seg + grid + base + th + sig;
    out[0] = seg; out[1] = grid; out[2] = base; out[3] = th; out[4] = sig; out[5] = total;
}

extern "C" void kernel_launch(void* const* d_in, const int* in_sizes, int n_in,
                              void* d_out, int out_size, void* d_ws, size_t ws_size,
                              hipStream_t stream) {
    const float* seg_pred  = (const float*)d_in[0];
    const int*   seg_tgt   = (const int*)d_in[1];
    const float* grid_pred = (const float*)d_in[2];
    const float* grid_tgt  = (const float*)d_in[3];
    const float* base_pred = (const float*)d_in[4];
    const float* base_tgt  = (const float*)d_in[5];
    const float* theta_p   = (const float*)d_in[6];
    const float* theta_g   = (const float*)d_in[7];
    const float* sig_p     = (const float*)d_in[8];
    const float* sig_t     = (const float*)d_in[9];
    const void*  maskp     = d_in[10];
    float* ws  = (float*)d_ws;
    float* out = (float*)d_out;

    hipMemsetAsync(d_ws, 0, WS_FLOATS * sizeof(float), stream);
    detect_mask_kernel<<<1, 256, 0, stream>>>((const unsigned char*)maskp, ws);
    seg_kernel<<<dim3(128, 8), 256, 0, stream>>>(seg_pred, seg_tgt, ws);
    grid_kernel<<<128, 256, 0, stream>>>((const float4*)grid_pred, (const float4*)grid_tgt, ws);
    baseline_kernel<<<384, 256, 0, stream>>>(base_pred, base_tgt, ws);
    signal_kernel<<<96, 256, 0, stream>>>(sig_p, sig_t, maskp, ws);
    finalize_kernel<<<1, 1, 0, stream>>>(theta_p, theta_g, ws, out);
}

// Round 2
// 328.382 us; speedup vs baseline: 1.2861x; 1.2861x over previous
//
#include <hip/hip_runtime.h>
#include <math.h>

// ---------------- workspace layout (floats) ----------------
#define WS_SEG_NLL    0    // 8 (per b)
#define WS_SEG_VALID  8    // 8
#define WS_INTER      16   // 104 (b*13+c)
#define WS_PSUM       120  // 104
#define WS_OHCNT      224  // 104
#define WS_GRID_BCE   328
#define WS_GRID_INTER 329
#define WS_GRID_PSUM  330
#define WS_GRID_TSUM  331
#define WS_BASE_BCE   332
#define WS_SIG_ABS    333
#define WS_SIG_CNT    334
#define WS_SIG_CORR   335
#define WS_SIG_NV     336
#define WS_FLOATS     338

__device__ inline float wave_sum(float v) {
    #pragma unroll
    for (int o = 32; o > 0; o >>= 1) v += __shfl_down(v, o, 64);
    return v;
}

// block reduce, result broadcast to all threads. OP: 0 sum, 1 min, 2 max
template <int OP>
__device__ inline float blk_red(float v, float* sb) {
    #pragma unroll
    for (int o = 32; o > 0; o >>= 1) {
        float u = __shfl_down(v, o, 64);
        v = (OP == 0) ? (v + u) : ((OP == 1) ? fminf(v, u) : fmaxf(v, u));
    }
    __syncthreads();                     // protect sb from previous use
    if ((threadIdx.x & 63) == 0) sb[threadIdx.x >> 6] = v;
    __syncthreads();
    const int nw = blockDim.x >> 6;
    float r = sb[0];
    for (int w = 1; w < nw; w++) {
        float u = sb[w];
        r = (OP == 0) ? (r + u) : ((OP == 1) ? fminf(r, u) : fmaxf(r, u));
    }
    return r;
}

// ---------------- seg: CE(ignore=255) + dice stats, float4 ----------------
__global__ __launch_bounds__(256) void seg_kernel(const float4* __restrict__ pred4,
                                                  const int4* __restrict__ tgt4,
                                                  float* __restrict__ ws) {
    const int b = blockIdx.y;
    const int HW  = 512 * 512;
    const int HW4 = HW / 4;
    const float4* predb = pred4 + (size_t)b * 13 * HW4;
    const int4* tgtb = tgt4 + (size_t)b * HW4;

    float psum[13], inter[13], cnt13[13];
    #pragma unroll
    for (int c = 0; c < 13; c++) { psum[c] = 0.f; inter[c] = 0.f; cnt13[c] = 0.f; }
    float nll = 0.f, nval = 0.f;

    const int stride = gridDim.x * blockDim.x;
    for (int i = blockIdx.x * blockDim.x + threadIdx.x; i < HW4; i += stride) {
        float4 x4[13];
        #pragma unroll
        for (int c = 0; c < 13; c++) x4[c] = predb[(size_t)c * HW4 + i];
        const int4 t4 = tgtb[i];
        const int ta[4] = {t4.x, t4.y, t4.z, t4.w};
        #pragma unroll
        for (int k = 0; k < 4; k++) {
            float x[13];
            #pragma unroll
            for (int c = 0; c < 13; c++)
                x[c] = (k == 0) ? x4[c].x : (k == 1) ? x4[c].y : (k == 2) ? x4[c].z : x4[c].w;
            const int t = ta[k];
            float m = x[0];
            #pragma unroll
            for (int c = 1; c < 13; c++) m = fmaxf(m, x[c]);
            float xt = x[0];
            #pragma unroll
            for (int c = 1; c < 13; c++) xt = (c == t) ? x[c] : xt;
            float se = 0.f;
            #pragma unroll
            for (int c = 0; c < 13; c++) { x[c] = __expf(x[c] - m); se += x[c]; }
            const float inv = 1.0f / se;
            #pragma unroll
            for (int c = 0; c < 13; c++) {
                const float p = x[c] * inv;
                psum[c] += p;
                const bool sel = (c == t);
                inter[c] += sel ? p : 0.f;
                cnt13[c] += sel ? 1.f : 0.f;
            }
            const bool valid = (t != 255);
            nll  += valid ? (m + __logf(se) - xt) : 0.f;
            nval += valid ? 1.f : 0.f;
        }
    }

    __shared__ float sred[41];
    if (threadIdx.x < 41) sred[threadIdx.x] = 0.f;
    __syncthreads();
    const bool lane0 = (threadIdx.x & 63) == 0;
    #pragma unroll
    for (int c = 0; c < 13; c++) {
        float a = wave_sum(psum[c]);  if (lane0) atomicAdd(&sred[c], a);
        float d = wave_sum(inter[c]); if (lane0) atomicAdd(&sred[13 + c], d);
        float e = wave_sum(cnt13[c]); if (lane0) atomicAdd(&sred[26 + c], e);
    }
    { float a = wave_sum(nll);  if (lane0) atomicAdd(&sred[39], a); }
    { float a = wave_sum(nval); if (lane0) atomicAdd(&sred[40], a); }
    __syncthreads();
    if (threadIdx.x < 13) {
        atomicAdd(&ws[WS_PSUM  + b * 13 + threadIdx.x], sred[threadIdx.x]);
        atomicAdd(&ws[WS_INTER + b * 13 + threadIdx.x], sred[13 + threadIdx.x]);
        atomicAdd(&ws[WS_OHCNT + b * 13 + threadIdx.x], sred[26 + threadIdx.x]);
    }
    if (threadIdx.x == 64) atomicAdd(&ws[WS_SEG_NLL + b],   sred[39]);
    if (threadIdx.x == 65) atomicAdd(&ws[WS_SEG_VALID + b], sred[40]);
}

// ---------------- grid: BCE + dice scalars ----------------
__global__ __launch_bounds__(256) void grid_kernel(const float4* __restrict__ gp,
                                                   const float4* __restrict__ gt,
                                                   float* __restrict__ ws) {
    const int N4 = 2097152 / 4;
    float bce = 0.f, inter = 0.f, ps = 0.f, ts = 0.f;
    const int stride = gridDim.x * blockDim.x;
    for (int i = blockIdx.x * blockDim.x + threadIdx.x; i < N4; i += stride) {
        const float4 p4 = gp[i];
        const float4 t4 = gt[i];
        const float pa[4] = {p4.x, p4.y, p4.z, p4.w};
        const float ta[4] = {t4.x, t4.y, t4.z, t4.w};
        #pragma unroll
        for (int k = 0; k < 4; k++) {
            const float p = pa[k], t = ta[k];
            const float pc  = fminf(fmaxf(p, 1e-12f), 1.0f);
            const float qc  = fminf(fmaxf(1.f - p, 1e-12f), 1.0f);
            const float lp  = fmaxf(__logf(pc), -100.f);
            const float l1p = fmaxf(__logf(qc), -100.f);
            bce  -= t * lp + (1.f - t) * l1p;
            inter += p * t;
            ps += p;
            ts += t;
        }
    }
    __shared__ float s4[4];
    if (threadIdx.x < 4) s4[threadIdx.x] = 0.f;
    __syncthreads();
    const bool lane0 = (threadIdx.x & 63) == 0;
    { float a = wave_sum(bce);   if (lane0) atomicAdd(&s4[0], a); }
    { float a = wave_sum(inter); if (lane0) atomicAdd(&s4[1], a); }
    { float a = wave_sum(ps);    if (lane0) atomicAdd(&s4[2], a); }
    { float a = wave_sum(ts);    if (lane0) atomicAdd(&s4[3], a); }
    __syncthreads();
    if (threadIdx.x == 0) {
        atomicAdd(&ws[WS_GRID_BCE],   s4[0]);
        atomicAdd(&ws[WS_GRID_INTER], s4[1]);
        atomicAdd(&ws[WS_GRID_PSUM],  s4[2]);
        atomicAdd(&ws[WS_GRID_TSUM],  s4[3]);
    }
}

// ---------------- baseline: bilinear(align_corners) gather + BCE ----------------
__global__ __launch_bounds__(256) void baseline_kernel(const float* __restrict__ bp,
                                                       const float* __restrict__ bt,
                                                       float* __restrict__ ws) {
    const int idx = blockIdx.x * blockDim.x + threadIdx.x; // 0..98303
    float bce = 0.f;
    {
        const int w  = idx & 31;
        const int h  = (idx >> 5) & 31;
        const int bc = idx >> 10;                 // b*12 + c
        const float* img = bt + (size_t)bc * 262144;
        const float step = 511.0f / 31.0f;
        const float yy = h * step, xx = w * step;
        int y0 = (int)floorf(yy); int y1 = min(y0 + 1, 511); const float wy = yy - y0;
        int x0 = (int)floorf(xx); int x1 = min(x0 + 1, 511); const float wx = xx - x0;
        const float v00 = img[y0 * 512 + x0], v01 = img[y0 * 512 + x1];
        const float v10 = img[y1 * 512 + x0], v11 = img[y1 * 512 + x1];
        const float r0 = v00 * (1.f - wy) + v10 * wy;
        const float r1 = v01 * (1.f - wy) + v11 * wy;
        const float t  = r0 * (1.f - wx) + r1 * wx;
        const float p  = bp[idx];
        const float pc  = fminf(fmaxf(p, 1e-12f), 1.0f);
        const float qc  = fminf(fmaxf(1.f - p, 1e-12f), 1.0f);
        const float lp  = fmaxf(__logf(pc), -100.f);
        const float l1p = fmaxf(__logf(qc), -100.f);
        bce = -(t * lp + (1.f - t) * l1p);
    }
    __shared__ float sb[4];
    const float s = blk_red<0>(bce, sb);
    if (threadIdx.x == 0) atomicAdd(&ws[WS_BASE_BCE], s);
}

// ---------------- signal: masked normalize + MAE + Pearson ----------------
// Mask dtype detection is done per-block (redundantly, cheap): numpy bool ->
// 1 byte/elem, random nonzero at all byte offsets; int32 0/1 -> bytes at
// idx%4 != 0 are ALL zero. Scan first 3072 bytes (safe for both layouts:
// bool buffer is 480000 B, int32 buffer 1920000 B).
__global__ __launch_bounds__(256) void signal_kernel(const float* __restrict__ sp,
                                                     const float* __restrict__ st,
                                                     const void* __restrict__ mp,
                                                     float* __restrict__ ws) {
    const int T = 5000;
    const int bl = blockIdx.x;     // 0..95
    const int b = bl / 12, l = bl % 12;
    const float* ps = sp + (size_t)(b * 12 + l) * T;          // (B,12,T)
    const float* ts_base = st + (size_t)b * T * 12 + l;       // (B,T,12)
    const int* mi = (const int*)mp;
    const unsigned char* mb = (const unsigned char*)mp;
    const size_t mbase = (size_t)b * T * 12 + l;

    __shared__ float sb[4];
    __shared__ int s_flag;

    // --- mask dtype detection ---
    if (threadIdx.x == 0) s_flag = 0;
    __syncthreads();
    int f = 0;
    for (int i = threadIdx.x; i < 3072; i += blockDim.x)
        if ((i & 3) && mb[i]) f = 1;
    if (__any(f) && (threadIdx.x & 63) == 0) atomicOr(&s_flag, 1);
    __syncthreads();
    const bool m32 = (s_flag == 0);   // all non-aligned bytes zero => int32

    float cnt = 0.f;
    float mnp = __builtin_inff(), mxp = -__builtin_inff();
    float mnt = __builtin_inff(), mxt = -__builtin_inff();
    for (int t = threadIdx.x; t < T; t += blockDim.x) {
        const bool m = m32 ? (mi[mbase + (size_t)t * 12] != 0)
                           : (mb[mbase + (size_t)t * 12] != 0);
        const float p  = ps[t];
        const float tv = ts_base[(size_t)t * 12];
        if (m) {
            cnt += 1.f;
            mnp = fminf(mnp, p);  mxp = fmaxf(mxp, p);
            mnt = fminf(mnt, tv); mxt = fmaxf(mxt, tv);
        }
    }
    cnt = blk_red<0>(cnt, sb);
    mnp = blk_red<1>(mnp, sb); mxp = blk_red<2>(mxp, sb);
    mnt = blk_red<1>(mnt, sb); mxt = blk_red<2>(mxt, sb);

    const float rngp = mxp - mnp, rngt = mxt - mnt;
    const bool okp = (cnt >= 2.f) && (rngp >= 1e-6f);
    const bool okt = (cnt >= 2.f) && (rngt >= 1e-6f);
    const float mnp_s = okp ? mnp : 0.f, rp = okp ? rngp : 1.f;
    const float mnt_s = okt ? mnt : 0.f, rt = okt ? rngt : 1.f;
    const float invp = 2.f / (rp + 1e-8f), invt = 2.f / (rt + 1e-8f);

    float S_p = 0.f, S_t = 0.f, S_pt = 0.f, S_pp = 0.f, S_tt = 0.f, S_abs = 0.f;
    for (int t = threadIdx.x; t < T; t += blockDim.x) {
        const bool m = m32 ? (mi[mbase + (size_t)t * 12] != 0)
                           : (mb[mbase + (size_t)t * 12] != 0);
        const float p  = ps[t];
        const float tv = ts_base[(size_t)t * 12];
        const float pn = (m && okp) ? ((p  - mnp_s) * invp - 1.f) : 0.f;
        const float tn = (m && okt) ? ((tv - mnt_s) * invt - 1.f) : 0.f;
        S_p += pn; S_t += tn;
        S_pt += pn * tn; S_pp += pn * pn; S_tt += tn * tn;
        S_abs += m ? fabsf(pn - tn) : 0.f;
    }
    S_p  = blk_red<0>(S_p, sb);
    S_t  = blk_red<0>(S_t, sb);
    S_pt = blk_red<0>(S_pt, sb);
    S_pp = blk_red<0>(S_pp, sb);
    S_tt = blk_red<0>(S_tt, sb);
    S_abs = blk_red<0>(S_abs, sb);

    if (threadIdx.x == 0) {
        const float cs = fmaxf(cnt, 1.f);
        const float pm = S_p / cs, tm = S_t / cs;
        const float num = S_pt - pm * S_t - tm * S_p + pm * tm * cnt;
        const float psd = sqrtf(fmaxf(S_pp - 2.f * pm * S_p + pm * pm * cnt, 0.f) + 1e-6f);
        const float tsd = sqrtf(fmaxf(S_tt - 2.f * tm * S_t + tm * tm * cnt, 0.f) + 1e-6f);
        float corr = num / (psd * tsd + 1e-6f);
        corr = fminf(fmaxf(corr, -1.f), 1.f);
        const float valid = (cnt >= 10.f) ? 1.f : 0.f;
        atomicAdd(&ws[WS_SIG_ABS],  S_abs);
        atomicAdd(&ws[WS_SIG_CNT],  cnt);
        atomicAdd(&ws[WS_SIG_CORR], corr * valid);
        atomicAdd(&ws[WS_SIG_NV],   valid);
    }
}

// ---------------- finalize (incl. theta), 1 block x 128 threads ----------------
__global__ __launch_bounds__(128) void finalize_kernel(const float* __restrict__ tp,
                                                       const float* __restrict__ tg,
                                                       const float* __restrict__ ws,
                                                       float* __restrict__ out) {
    __shared__ float s_d, s_nll, s_nv, s_th;
    if (threadIdx.x == 0) { s_d = 0.f; s_nll = 0.f; s_nv = 0.f; s_th = 0.f; }
    __syncthreads();
    const int t = threadIdx.x;
    float d = 0.f, nll = 0.f, nv = 0.f, th = 0.f;
    if (t < 104) {
        const float it = ws[WS_INTER + t], p = ws[WS_PSUM + t], oh = ws[WS_OHCNT + t];
        d = (2.f * it + 1e-7f) / (p + oh + 1e-7f);
    }
    if (t < 8) { nll = ws[WS_SEG_NLL + t]; nv = ws[WS_SEG_VALID + t]; }
    if (t < 48) th = fabsf(tp[t] - tg[t]);
    d = wave_sum(d); nll = wave_sum(nll); nv = wave_sum(nv); th = wave_sum(th);
    if ((t & 63) == 0) {
        atomicAdd(&s_d, d); atomicAdd(&s_nll, nll);
        atomicAdd(&s_nv, nv); atomicAdd(&s_th, th);
    }
    __syncthreads();
    if (t == 0) {
        const float ce = s_nll / fmaxf(s_nv, 1.f);
        const float seg = (ce + (1.f - s_d / 104.f)) * 1.0f;
        const float bce_g = ws[WS_GRID_BCE] / 2097152.f;
        const float gd = 1.f - (2.f * ws[WS_GRID_INTER] + 1e-7f) /
                               (ws[WS_GRID_PSUM] + ws[WS_GRID_TSUM] + 1e-7f);
        const float grid = (bce_g + gd) * 0.5f;
        const float base = (ws[WS_BASE_BCE] / 98304.f) * 0.8f;
        const float theta = (s_th / 48.f) * 0.3f;
        const float mae = ws[WS_SIG_ABS] / (ws[WS_SIG_CNT] + 1e-7f);
        const float nvs = ws[WS_SIG_NV];
        const float pear = (nvs > 0.f) ? (1.f - ws[WS_SIG_CORR] / fmaxf(nvs, 1.f)) : 1.f;
        const float sig = (mae + pear) * 2.0f;
        const float total = seg + grid + base + theta + sig;
        out[0] = seg; out[1] = grid; out[2] = base; out[3] = theta; out[4] = sig;
        out[5] = total;
    }
}

extern "C" void kernel_launch(void* const* d_in, const int* in_sizes, int n_in,
                              void* d_out, int out_size, void* d_ws, size_t ws_size,
                              hipStream_t stream) {
    const float* seg_pred  = (const float*)d_in[0];
    const int*   seg_tgt   = (const int*)d_in[1];
    const float* grid_pred = (const float*)d_in[2];
    const float* grid_tgt  = (const float*)d_in[3];
    const float* base_pred = (const float*)d_in[4];
    const float* base_tgt  = (const float*)d_in[5];
    const float* theta_p   = (const float*)d_in[6];
    const float* theta_g   = (const float*)d_in[7];
    const float* sig_p     = (const float*)d_in[8];
    const float* sig_t     = (const float*)d_in[9];
    const void*  maskp     = d_in[10];
    float* ws  = (float*)d_ws;
    float* out = (float*)d_out;

    hipMemsetAsync(d_ws, 0, WS_FLOATS * sizeof(float), stream);
    seg_kernel<<<dim3(128, 8), 256, 0, stream>>>((const float4*)seg_pred,
                                                 (const int4*)seg_tgt, ws);
    grid_kernel<<<128, 256, 0, stream>>>((const float4*)grid_pred, (const float4*)grid_tgt, ws);
    baseline_kernel<<<384, 256, 0, stream>>>(base_pred, base_tgt, ws);
    signal_kernel<<<96, 256, 0, stream>>>(sig_p, sig_t, maskp, ws);
    finalize_kernel<<<1, 128, 0, stream>>>(theta_p, theta_g, ws, out);
}

// Round 3
// 304.780 us; speedup vs baseline: 1.3856x; 1.0774x over previous
//
#include <hip/hip_runtime.h>
#include <math.h>

// ---------------- workspace layout (floats) ----------------
#define WS_SEG_NLL    0    // 8 (per b)
#define WS_SEG_VALID  8    // 8
#define WS_INTER      16   // 104 (b*13+c)
#define WS_PSUM       120  // 104
#define WS_OHCNT      224  // 104
#define WS_GRID_BCE   328
#define WS_GRID_INTER 329
#define WS_GRID_PSUM  330
#define WS_GRID_TSUM  331
#define WS_BASE_BCE   332
#define WS_SIG_ABS    333
#define WS_SIG_CNT    334
#define WS_SIG_CORR   335
#define WS_SIG_NV     336
#define WS_MASK_FLAG  337  // 1.0 => mask stored as int32, 0.0 => uint8
#define WS_DONE       338  // int completion counter
#define WS_SIGSTATS   340  // 96*5: cnt,mnp,mxp,mnt,mxt per (b,l)
#define WS_FLOATS     820

// mega-kernel block partition
#define SEG_NB   2048
#define GRID_NB  256
#define BASE_NB  384
#define SIGA_NB  96
#define TOTAL_NB (SEG_NB + GRID_NB + BASE_NB + SIGA_NB)

__device__ inline float wave_sum(float v) {
    #pragma unroll
    for (int o = 32; o > 0; o >>= 1) v += __shfl_down(v, o, 64);
    return v;
}

// block reduce, result broadcast. OP: 0 sum, 1 min, 2 max. sb: >= nwaves floats
template <int OP>
__device__ inline float blk_red(float v, float* sb) {
    #pragma unroll
    for (int o = 32; o > 0; o >>= 1) {
        float u = __shfl_down(v, o, 64);
        v = (OP == 0) ? (v + u) : ((OP == 1) ? fminf(v, u) : fmaxf(v, u));
    }
    __syncthreads();
    if ((threadIdx.x & 63) == 0) sb[threadIdx.x >> 6] = v;
    __syncthreads();
    const int nw = blockDim.x >> 6;
    float r = sb[0];
    for (int w = 1; w < nw; w++) {
        float u = sb[w];
        r = (OP == 0) ? (r + u) : ((OP == 1) ? fminf(r, u) : fmaxf(r, u));
    }
    return r;
}

// ---------------- seg part: CE(ignore=255) + dice stats ----------------
// float2 loads (26 live regs), ballot-based counts (scalar regs), LDS atomic
// for per-target-class prob => aims for <=64 VGPR bracket / high occupancy.
__device__ void seg_part(int sb_idx, const float2* __restrict__ pred2,
                         const int2* __restrict__ tgt2, float* __restrict__ ws) {
    const int b  = sb_idx >> 8;       // batch
    const int xb = sb_idx & 255;      // block within batch
    const int HW2 = 131072;           // 512*512/2
    const float2* predb = pred2 + (size_t)b * 13 * HW2;
    const int2*   tgtb  = tgt2 + (size_t)b * HW2;

    __shared__ float s_inter[13];
    __shared__ float s_psum[13];
    __shared__ int   s_cnt[13];
    __shared__ float s_nll;
    __shared__ int   s_nval;
    if (threadIdx.x < 13) { s_inter[threadIdx.x] = 0.f; s_psum[threadIdx.x] = 0.f; s_cnt[threadIdx.x] = 0; }
    if (threadIdx.x == 13) s_nll = 0.f;
    if (threadIdx.x == 14) s_nval = 0;
    __syncthreads();

    float psum[13];
    #pragma unroll
    for (int c = 0; c < 13; c++) psum[c] = 0.f;
    int cnt[13];
    #pragma unroll
    for (int c = 0; c < 13; c++) cnt[c] = 0;
    float nll = 0.f;
    int nval = 0;

    #pragma unroll
    for (int it = 0; it < 2; it++) {
        const int j = xb * 256 + threadIdx.x + it * 65536;   // float2-pair index
        float2 x2[13];
        #pragma unroll
        for (int c = 0; c < 13; c++) x2[c] = predb[c * HW2 + j];
        const int2 t2 = tgtb[j];
        #pragma unroll
        for (int k = 0; k < 2; k++) {
            const int t = (k == 0) ? t2.x : t2.y;
            float x[13];
            #pragma unroll
            for (int c = 0; c < 13; c++) x[c] = (k == 0) ? x2[c].x : x2[c].y;
            float m = x[0];
            #pragma unroll
            for (int c = 1; c < 13; c++) m = fmaxf(m, x[c]);
            float xt = x[0];
            #pragma unroll
            for (int c = 1; c < 13; c++) xt = (c == t) ? x[c] : xt;
            float se = 0.f;
            #pragma unroll
            for (int c = 0; c < 13; c++) { x[c] = __expf(x[c] - m); se += x[c]; }
            const float inv = __builtin_amdgcn_rcpf(se);
            #pragma unroll
            for (int c = 0; c < 13; c++) psum[c] += x[c] * inv;
            // one-hot counts: wave-uniform scalar accumulation
            #pragma unroll
            for (int c = 0; c < 13; c++) cnt[c] += __popcll(__ballot(t == c));
            nval += __popcll(__ballot(t != 255));
            const bool valid = (t != 255);
            if ((unsigned)t < 13u) {
                const float pt = __expf(xt - m) * inv;
                atomicAdd(&s_inter[t], pt);
            }
            nll += valid ? (m + __logf(se) - xt) : 0.f;
        }
    }

    const bool lane0 = (threadIdx.x & 63) == 0;
    #pragma unroll
    for (int c = 0; c < 13; c++) {
        float a = wave_sum(psum[c]);
        if (lane0) atomicAdd(&s_psum[c], a);
    }
    { float a = wave_sum(nll); if (lane0) atomicAdd(&s_nll, a); }
    if (lane0) {
        #pragma unroll
        for (int c = 0; c < 13; c++) atomicAdd(&s_cnt[c], cnt[c]);
        atomicAdd(&s_nval, nval);
    }
    __syncthreads();
    if (threadIdx.x < 13) {
        atomicAdd(&ws[WS_PSUM  + b * 13 + threadIdx.x], s_psum[threadIdx.x]);
        atomicAdd(&ws[WS_INTER + b * 13 + threadIdx.x], s_inter[threadIdx.x]);
        atomicAdd(&ws[WS_OHCNT + b * 13 + threadIdx.x], (float)s_cnt[threadIdx.x]);
    }
    if (threadIdx.x == 64) atomicAdd(&ws[WS_SEG_NLL + b],   s_nll);
    if (threadIdx.x == 65) atomicAdd(&ws[WS_SEG_VALID + b], (float)s_nval);
}

// ---------------- grid part: BCE + dice scalars ----------------
__device__ void grid_part(int gb, const float4* __restrict__ gp,
                          const float4* __restrict__ gt, float* __restrict__ ws) {
    const int N4 = 2097152 / 4;
    float bce = 0.f, inter = 0.f, ps = 0.f, ts = 0.f;
    const int stride = GRID_NB * 256;
    for (int i = gb * 256 + threadIdx.x; i < N4; i += stride) {
        const float4 p4 = gp[i];
        const float4 t4 = gt[i];
        const float pa[4] = {p4.x, p4.y, p4.z, p4.w};
        const float ta[4] = {t4.x, t4.y, t4.z, t4.w};
        #pragma unroll
        for (int k = 0; k < 4; k++) {
            const float p = pa[k], t = ta[k];
            const float pc  = fminf(fmaxf(p, 1e-12f), 1.0f);
            const float qc  = fminf(fmaxf(1.f - p, 1e-12f), 1.0f);
            const float lp  = fmaxf(__logf(pc), -100.f);
            const float l1p = fmaxf(__logf(qc), -100.f);
            bce  -= t * lp + (1.f - t) * l1p;
            inter += p * t;
            ps += p;
            ts += t;
        }
    }
    __shared__ float s4[4];
    if (threadIdx.x < 4) s4[threadIdx.x] = 0.f;
    __syncthreads();
    const bool lane0 = (threadIdx.x & 63) == 0;
    { float a = wave_sum(bce);   if (lane0) atomicAdd(&s4[0], a); }
    { float a = wave_sum(inter); if (lane0) atomicAdd(&s4[1], a); }
    { float a = wave_sum(ps);    if (lane0) atomicAdd(&s4[2], a); }
    { float a = wave_sum(ts);    if (lane0) atomicAdd(&s4[3], a); }
    __syncthreads();
    if (threadIdx.x == 0) {
        atomicAdd(&ws[WS_GRID_BCE],   s4[0]);
        atomicAdd(&ws[WS_GRID_INTER], s4[1]);
        atomicAdd(&ws[WS_GRID_PSUM],  s4[2]);
        atomicAdd(&ws[WS_GRID_TSUM],  s4[3]);
    }
}

// ---------------- baseline part: bilinear(align_corners) gather + BCE ----------------
__device__ void base_part(int bb, const float* __restrict__ bp,
                          const float* __restrict__ bt, float* __restrict__ ws) {
    const int idx = bb * 256 + threadIdx.x;   // 0..98303
    const int w  = idx & 31;
    const int h  = (idx >> 5) & 31;
    const int bc = idx >> 10;                 // b*12 + c
    const float* img = bt + (size_t)bc * 262144;
    const float step = 511.0f / 31.0f;
    const float yy = h * step, xx = w * step;
    int y0 = (int)floorf(yy); int y1 = min(y0 + 1, 511); const float wy = yy - y0;
    int x0 = (int)floorf(xx); int x1 = min(x0 + 1, 511); const float wx = xx - x0;
    const float v00 = img[y0 * 512 + x0], v01 = img[y0 * 512 + x1];
    const float v10 = img[y1 * 512 + x0], v11 = img[y1 * 512 + x1];
    const float r0 = v00 * (1.f - wy) + v10 * wy;
    const float r1 = v01 * (1.f - wy) + v11 * wy;
    const float t  = r0 * (1.f - wx) + r1 * wx;
    const float p  = bp[idx];
    const float pc  = fminf(fmaxf(p, 1e-12f), 1.0f);
    const float qc  = fminf(fmaxf(1.f - p, 1e-12f), 1.0f);
    const float lp  = fmaxf(__logf(pc), -100.f);
    const float l1p = fmaxf(__logf(qc), -100.f);
    const float bce = -(t * lp + (1.f - t) * l1p);

    __shared__ float sb[4];
    const float s = blk_red<0>(bce, sb);
    if (threadIdx.x == 0) atomicAdd(&ws[WS_BASE_BCE], s);
}

// ---------------- signal phase A: mask detect + per-(b,l) min/max/cnt ----------------
__device__ void sigA_part(int sl, const float* __restrict__ sp,
                          const float* __restrict__ st, const void* __restrict__ mp,
                          float* __restrict__ ws) {
    const int T = 5000;
    const int b = sl / 12, l = sl % 12;
    const float* ps = sp + (size_t)(b * 12 + l) * T;          // (B,12,T)
    const float* ts_base = st + (size_t)b * T * 12 + l;       // (B,T,12)
    const int* mi = (const int*)mp;
    const unsigned char* mb = (const unsigned char*)mp;
    const size_t mbase = (size_t)b * T * 12 + l;

    __shared__ float sb[4];
    __shared__ int s_flag;
    // mask dtype detect: int32 0/1 => bytes at idx%4!=0 are ALL zero.
    if (threadIdx.x == 0) s_flag = 0;
    __syncthreads();
    int f = 0;
    for (int i = threadIdx.x; i < 3072; i += blockDim.x)
        if ((i & 3) && mb[i]) f = 1;
    if (__any(f) && (threadIdx.x & 63) == 0) atomicOr(&s_flag, 1);
    __syncthreads();
    const bool m32 = (s_flag == 0);

    float cnt = 0.f;
    float mnp = __builtin_inff(), mxp = -__builtin_inff();
    float mnt = __builtin_inff(), mxt = -__builtin_inff();
    for (int t = threadIdx.x; t < T; t += blockDim.x) {
        const bool m = m32 ? (mi[mbase + (size_t)t * 12] != 0)
                           : (mb[mbase + (size_t)t * 12] != 0);
        const float p  = ps[t];
        const float tv = ts_base[(size_t)t * 12];
        if (m) {
            cnt += 1.f;
            mnp = fminf(mnp, p);  mxp = fmaxf(mxp, p);
            mnt = fminf(mnt, tv); mxt = fmaxf(mxt, tv);
        }
    }
    cnt = blk_red<0>(cnt, sb);
    mnp = blk_red<1>(mnp, sb); mxp = blk_red<2>(mxp, sb);
    mnt = blk_red<1>(mnt, sb); mxt = blk_red<2>(mxt, sb);

    if (threadIdx.x == 0) {
        float* o = ws + WS_SIGSTATS + sl * 5;
        o[0] = cnt; o[1] = mnp; o[2] = mxp; o[3] = mnt; o[4] = mxt;
        if (sl == 0) ws[WS_MASK_FLAG] = m32 ? 1.0f : 0.0f;
    }
}

// ---------------- mega kernel ----------------
__global__ __launch_bounds__(256) void mega_kernel(
        const float2* __restrict__ seg_pred, const int2* __restrict__ seg_tgt,
        const float4* __restrict__ grid_pred, const float4* __restrict__ grid_tgt,
        const float* __restrict__ base_pred, const float* __restrict__ base_tgt,
        const float* __restrict__ sig_p, const float* __restrict__ sig_t,
        const void* __restrict__ maskp, float* __restrict__ ws) {
    const int bx = blockIdx.x;
    if (bx < SEG_NB) {
        seg_part(bx, seg_pred, seg_tgt, ws);
    } else if (bx < SEG_NB + GRID_NB) {
        grid_part(bx - SEG_NB, grid_pred, grid_tgt, ws);
    } else if (bx < SEG_NB + GRID_NB + BASE_NB) {
        base_part(bx - SEG_NB - GRID_NB, base_pred, base_tgt, ws);
    } else {
        sigA_part(bx - SEG_NB - GRID_NB - BASE_NB, sig_p, sig_t, maskp, ws);
    }
}

// ---------------- signal phase B + finalize (last-block) ----------------
__global__ __launch_bounds__(256) void sigB_kernel(
        const float* __restrict__ sp, const float* __restrict__ st,
        const void* __restrict__ mp, const float* __restrict__ tp,
        const float* __restrict__ tg, float* __restrict__ ws,
        float* __restrict__ out) {
    const int T = 5000;
    const int sl = blockIdx.x;     // 0..95
    const int b = sl / 12, l = sl % 12;
    const float* ps = sp + (size_t)(b * 12 + l) * T;
    const float* ts_base = st + (size_t)b * T * 12 + l;
    const int* mi = (const int*)mp;
    const unsigned char* mb = (const unsigned char*)mp;
    const size_t mbase = (size_t)b * T * 12 + l;

    __shared__ float sb[4];
    const bool m32 = ws[WS_MASK_FLAG] > 0.5f;
    const float* stats = ws + WS_SIGSTATS + sl * 5;
    const float cnt = stats[0];
    const float mnp = stats[1], mxp = stats[2], mnt = stats[3], mxt = stats[4];

    const float rngp = mxp - mnp, rngt = mxt - mnt;
    const bool okp = (cnt >= 2.f) && (rngp >= 1e-6f);
    const bool okt = (cnt >= 2.f) && (rngt >= 1e-6f);
    const float mnp_s = okp ? mnp : 0.f, rp = okp ? rngp : 1.f;
    const float mnt_s = okt ? mnt : 0.f, rt = okt ? rngt : 1.f;
    const float invp = 2.f / (rp + 1e-8f), invt = 2.f / (rt + 1e-8f);

    float S_p = 0.f, S_t = 0.f, S_pt = 0.f, S_pp = 0.f, S_tt = 0.f, S_abs = 0.f;
    for (int t = threadIdx.x; t < T; t += blockDim.x) {
        const bool m = m32 ? (mi[mbase + (size_t)t * 12] != 0)
                           : (mb[mbase + (size_t)t * 12] != 0);
        const float p  = ps[t];
        const float tv = ts_base[(size_t)t * 12];
        const float pn = (m && okp) ? ((p  - mnp_s) * invp - 1.f) : 0.f;
        const float tn = (m && okt) ? ((tv - mnt_s) * invt - 1.f) : 0.f;
        S_p += pn; S_t += tn;
        S_pt += pn * tn; S_pp += pn * pn; S_tt += tn * tn;
        S_abs += m ? fabsf(pn - tn) : 0.f;
    }
    S_p  = blk_red<0>(S_p, sb);
    S_t  = blk_red<0>(S_t, sb);
    S_pt = blk_red<0>(S_pt, sb);
    S_pp = blk_red<0>(S_pp, sb);
    S_tt = blk_red<0>(S_tt, sb);
    S_abs = blk_red<0>(S_abs, sb);

    __shared__ int s_last;
    if (threadIdx.x == 0) {
        const float cs = fmaxf(cnt, 1.f);
        const float pm = S_p / cs, tm = S_t / cs;
        const float num = S_pt - pm * S_t - tm * S_p + pm * tm * cnt;
        const float psd = sqrtf(fmaxf(S_pp - 2.f * pm * S_p + pm * pm * cnt, 0.f) + 1e-6f);
        const float tsd = sqrtf(fmaxf(S_tt - 2.f * tm * S_t + tm * tm * cnt, 0.f) + 1e-6f);
        float corr = num / (psd * tsd + 1e-6f);
        corr = fminf(fmaxf(corr, -1.f), 1.f);
        const float valid = (cnt >= 10.f) ? 1.f : 0.f;
        atomicAdd(&ws[WS_SIG_ABS],  S_abs);
        atomicAdd(&ws[WS_SIG_CNT],  cnt);
        atomicAdd(&ws[WS_SIG_CORR], corr * valid);
        atomicAdd(&ws[WS_SIG_NV],   valid);
        __threadfence();
        const int old = atomicAdd((int*)(ws + WS_DONE), 1);
        s_last = (old == 95) ? 1 : 0;
    }
    __syncthreads();
    if (!s_last) return;

    // ---- finalize (one block) ----
    __shared__ float s_d, s_nll, s_nv, s_th;
    if (threadIdx.x == 0) { s_d = 0.f; s_nll = 0.f; s_nv = 0.f; s_th = 0.f; }
    __syncthreads();
    const int t = threadIdx.x;
    float d = 0.f, nll = 0.f, nv = 0.f, th = 0.f;
    if (t < 104) {
        const float it = ws[WS_INTER + t], p = ws[WS_PSUM + t], oh = ws[WS_OHCNT + t];
        d = (2.f * it + 1e-7f) / (p + oh + 1e-7f);
    }
    if (t < 8) { nll = ws[WS_SEG_NLL + t]; nv = ws[WS_SEG_VALID + t]; }
    if (t < 48) th = fabsf(tp[t] - tg[t]);
    d = wave_sum(d); nll = wave_sum(nll); nv = wave_sum(nv); th = wave_sum(th);
    if ((t & 63) == 0) {
        atomicAdd(&s_d, d); atomicAdd(&s_nll, nll);
        atomicAdd(&s_nv, nv); atomicAdd(&s_th, th);
    }
    __syncthreads();
    if (t == 0) {
        const float ce = s_nll / fmaxf(s_nv, 1.f);
        const float seg = (ce + (1.f - s_d / 104.f)) * 1.0f;
        const float bce_g = ws[WS_GRID_BCE] / 2097152.f;
        const float gd = 1.f - (2.f * ws[WS_GRID_INTER] + 1e-7f) /
                               (ws[WS_GRID_PSUM] + ws[WS_GRID_TSUM] + 1e-7f);
        const float grid = (bce_g + gd) * 0.5f;
        const float base = (ws[WS_BASE_BCE] / 98304.f) * 0.8f;
        const float theta = (s_th / 48.f) * 0.3f;
        // phase-B sums were written by other blocks' device-scope atomics in
        // THIS dispatch -> read coherently via atomic RMW (+0), not plain loads
        // (per-XCD L2s are not cross-coherent).
        const float sabs = atomicAdd(&ws[WS_SIG_ABS],  0.f);
        const float scnt = atomicAdd(&ws[WS_SIG_CNT],  0.f);
        const float scor = atomicAdd(&ws[WS_SIG_CORR], 0.f);
        const float snv  = atomicAdd(&ws[WS_SIG_NV],   0.f);
        const float mae = sabs / (scnt + 1e-7f);
        const float pear = (snv > 0.f) ? (1.f - scor / fmaxf(snv, 1.f)) : 1.f;
        const float sig = (mae + pear) * 2.0f;
        const float total = seg + grid + base + theta + sig;
        out[0] = seg; out[1] = grid; out[2] = base; out[3] = theta; out[4] = sig;
        out[5] = total;
    }
}

extern "C" void kernel_launch(void* const* d_in, const int* in_sizes, int n_in,
                              void* d_out, int out_size, void* d_ws, size_t ws_size,
                              hipStream_t stream) {
    const float* seg_pred  = (const float*)d_in[0];
    const int*   seg_tgt   = (const int*)d_in[1];
    const float* grid_pred = (const float*)d_in[2];
    const float* grid_tgt  = (const float*)d_in[3];
    const float* base_pred = (const float*)d_in[4];
    const float* base_tgt  = (const float*)d_in[5];
    const float* theta_p   = (const float*)d_in[6];
    const float* theta_g   = (const float*)d_in[7];
    const float* sig_p     = (const float*)d_in[8];
    const float* sig_t     = (const float*)d_in[9];
    const void*  maskp     = d_in[10];
    float* ws  = (float*)d_ws;
    float* out = (float*)d_out;

    hipMemsetAsync(d_ws, 0, WS_FLOATS * sizeof(float), stream);
    mega_kernel<<<TOTAL_NB, 256, 0, stream>>>(
        (const float2*)seg_pred, (const int2*)seg_tgt,
        (const float4*)grid_pred, (const float4*)grid_tgt,
        base_pred, base_tgt, sig_p, sig_t, maskp, ws);
    sigB_kernel<<<96, 256, 0, stream>>>(sig_p, sig_t, maskp, theta_p, theta_g, ws, out);
}

// Round 4
// 303.440 us; speedup vs baseline: 1.3918x; 1.0044x over previous
//
#include <hip/hip_runtime.h>
#include <math.h>

// ---------------- workspace layout (floats) ----------------
#define WS_SEG_NLL    0    // 8 (per b)
#define WS_SEG_VALID  8    // 8
#define WS_INTER      16   // 104 (b*13+c)
#define WS_PSUM       120  // 104
#define WS_OHCNT      224  // 104
#define WS_GRID_BCE   328
#define WS_GRID_INTER 329
#define WS_GRID_PSUM  330
#define WS_GRID_TSUM  331
#define WS_BASE_BCE   332
#define WS_SIG_ABS    333
#define WS_SIG_CNT    334
#define WS_SIG_CORR   335
#define WS_SIG_NV     336
#define WS_MASK_FLAG  337  // 1.0 => mask stored as int32, 0.0 => uint8
#define WS_DONE       338  // int completion counter
#define WS_SIGSTATS   340  // 96*5: cnt,mnp,mxp,mnt,mxt per (b,l)
#define WS_FLOATS     820

// mega-kernel block partition (seg first: longest-running blocks dispatch first)
#define SEG_NB   2048
#define GRID_NB  256
#define BASE_NB  384
#define SIGA_NB  96
#define TOTAL_NB (SEG_NB + GRID_NB + BASE_NB + SIGA_NB)

__device__ inline float wave_sum(float v) {
    #pragma unroll
    for (int o = 32; o > 0; o >>= 1) v += __shfl_down(v, o, 64);
    return v;
}

// block reduce, result broadcast. OP: 0 sum, 1 min, 2 max. sb: >= nwaves floats
template <int OP>
__device__ inline float blk_red(float v, float* sb) {
    #pragma unroll
    for (int o = 32; o > 0; o >>= 1) {
        float u = __shfl_down(v, o, 64);
        v = (OP == 0) ? (v + u) : ((OP == 1) ? fminf(v, u) : fmaxf(v, u));
    }
    __syncthreads();
    if ((threadIdx.x & 63) == 0) sb[threadIdx.x >> 6] = v;
    __syncthreads();
    const int nw = blockDim.x >> 6;
    float r = sb[0];
    for (int w = 1; w < nw; w++) {
        float u = sb[w];
        r = (OP == 0) ? (r + u) : ((OP == 1) ? fminf(r, u) : fmaxf(r, u));
    }
    return r;
}

// ---------------- seg part: CE(ignore=255) + dice stats ----------------
// float4 loads: 13 x 1KB-per-wave loads in flight (needs the 128-VGPR budget
// from __launch_bounds__(256,4); R3's 40-VGPR allocation split the burst and
// capped the kernel at ~870 GB/s).
__device__ void seg_part(int sb_idx, const float4* __restrict__ pred4,
                         const int4* __restrict__ tgt4, float* __restrict__ ws) {
    const int b  = sb_idx >> 8;       // batch (256 blocks per batch)
    const int xb = sb_idx & 255;      // block within batch
    const int HW4 = 65536;            // 512*512/4
    const float4* predb = pred4 + (size_t)b * 13 * HW4;
    const int4*   tgtb  = tgt4 + (size_t)b * HW4;

    __shared__ float s_inter[13];
    __shared__ float s_psum[13];
    __shared__ int   s_cnt[13];
    __shared__ float s_nll;
    __shared__ int   s_nval;
    if (threadIdx.x < 13) { s_inter[threadIdx.x] = 0.f; s_psum[threadIdx.x] = 0.f; s_cnt[threadIdx.x] = 0; }
    if (threadIdx.x == 13) s_nll = 0.f;
    if (threadIdx.x == 14) s_nval = 0;
    __syncthreads();

    float psum[13];
    #pragma unroll
    for (int c = 0; c < 13; c++) psum[c] = 0.f;
    int cnt[13];
    #pragma unroll
    for (int c = 0; c < 13; c++) cnt[c] = 0;
    float nll = 0.f;
    int nval = 0;

    const int j = xb * 256 + threadIdx.x;     // float4 index within batch
    float4 x4[13];
    #pragma unroll
    for (int c = 0; c < 13; c++) x4[c] = predb[c * HW4 + j];
    const int4 t4 = tgtb[j];

    #pragma unroll
    for (int k = 0; k < 4; k++) {
        const int t = (k == 0) ? t4.x : (k == 1) ? t4.y : (k == 2) ? t4.z : t4.w;
        float x[13];
        #pragma unroll
        for (int c = 0; c < 13; c++)
            x[c] = (k == 0) ? x4[c].x : (k == 1) ? x4[c].y : (k == 2) ? x4[c].z : x4[c].w;
        float m = x[0];
        #pragma unroll
        for (int c = 1; c < 13; c++) m = fmaxf(m, x[c]);
        float xt = x[0];
        #pragma unroll
        for (int c = 1; c < 13; c++) xt = (c == t) ? x[c] : xt;
        float se = 0.f;
        #pragma unroll
        for (int c = 0; c < 13; c++) { x[c] = __expf(x[c] - m); se += x[c]; }
        const float inv = __builtin_amdgcn_rcpf(se);
        #pragma unroll
        for (int c = 0; c < 13; c++) psum[c] += x[c] * inv;
        // one-hot counts: wave-uniform scalar accumulation
        #pragma unroll
        for (int c = 0; c < 13; c++) cnt[c] += __popcll(__ballot(t == c));
        nval += __popcll(__ballot(t != 255));
        const bool valid = (t != 255);
        if ((unsigned)t < 13u) {
            const float pt = __expf(xt - m) * inv;
            atomicAdd(&s_inter[t], pt);
        }
        nll += valid ? (m + __logf(se) - xt) : 0.f;
    }

    const bool lane0 = (threadIdx.x & 63) == 0;
    #pragma unroll
    for (int c = 0; c < 13; c++) {
        float a = wave_sum(psum[c]);
        if (lane0) atomicAdd(&s_psum[c], a);
    }
    { float a = wave_sum(nll); if (lane0) atomicAdd(&s_nll, a); }
    if (lane0) {
        #pragma unroll
        for (int c = 0; c < 13; c++) atomicAdd(&s_cnt[c], cnt[c]);
        atomicAdd(&s_nval, nval);
    }
    __syncthreads();
    if (threadIdx.x < 13) {
        atomicAdd(&ws[WS_PSUM  + b * 13 + threadIdx.x], s_psum[threadIdx.x]);
        atomicAdd(&ws[WS_INTER + b * 13 + threadIdx.x], s_inter[threadIdx.x]);
        atomicAdd(&ws[WS_OHCNT + b * 13 + threadIdx.x], (float)s_cnt[threadIdx.x]);
    }
    if (threadIdx.x == 64) atomicAdd(&ws[WS_SEG_NLL + b],   s_nll);
    if (threadIdx.x == 65) atomicAdd(&ws[WS_SEG_VALID + b], (float)s_nval);
}

// ---------------- grid part: BCE + dice scalars ----------------
__device__ void grid_part(int gb, const float4* __restrict__ gp,
                          const float4* __restrict__ gt, float* __restrict__ ws) {
    const int N4 = 2097152 / 4;
    float bce = 0.f, inter = 0.f, ps = 0.f, ts = 0.f;
    const int stride = GRID_NB * 256;
    for (int i = gb * 256 + threadIdx.x; i < N4; i += stride) {
        const float4 p4 = gp[i];
        const float4 t4 = gt[i];
        const float pa[4] = {p4.x, p4.y, p4.z, p4.w};
        const float ta[4] = {t4.x, t4.y, t4.z, t4.w};
        #pragma unroll
        for (int k = 0; k < 4; k++) {
            const float p = pa[k], t = ta[k];
            const float pc  = fminf(fmaxf(p, 1e-12f), 1.0f);
            const float qc  = fminf(fmaxf(1.f - p, 1e-12f), 1.0f);
            const float lp  = fmaxf(__logf(pc), -100.f);
            const float l1p = fmaxf(__logf(qc), -100.f);
            bce  -= t * lp + (1.f - t) * l1p;
            inter += p * t;
            ps += p;
            ts += t;
        }
    }
    __shared__ float s4[4];
    if (threadIdx.x < 4) s4[threadIdx.x] = 0.f;
    __syncthreads();
    const bool lane0 = (threadIdx.x & 63) == 0;
    { float a = wave_sum(bce);   if (lane0) atomicAdd(&s4[0], a); }
    { float a = wave_sum(inter); if (lane0) atomicAdd(&s4[1], a); }
    { float a = wave_sum(ps);    if (lane0) atomicAdd(&s4[2], a); }
    { float a = wave_sum(ts);    if (lane0) atomicAdd(&s4[3], a); }
    __syncthreads();
    if (threadIdx.x == 0) {
        atomicAdd(&ws[WS_GRID_BCE],   s4[0]);
        atomicAdd(&ws[WS_GRID_INTER], s4[1]);
        atomicAdd(&ws[WS_GRID_PSUM],  s4[2]);
        atomicAdd(&ws[WS_GRID_TSUM],  s4[3]);
    }
}

// ---------------- baseline part: bilinear(align_corners) gather + BCE ----------------
__device__ void base_part(int bb, const float* __restrict__ bp,
                          const float* __restrict__ bt, float* __restrict__ ws) {
    const int idx = bb * 256 + threadIdx.x;   // 0..98303
    const int w  = idx & 31;
    const int h  = (idx >> 5) & 31;
    const int bc = idx >> 10;                 // b*12 + c
    const float* img = bt + (size_t)bc * 262144;
    const float step = 511.0f / 31.0f;
    const float yy = h * step, xx = w * step;
    int y0 = (int)floorf(yy); int y1 = min(y0 + 1, 511); const float wy = yy - y0;
    int x0 = (int)floorf(xx); int x1 = min(x0 + 1, 511); const float wx = xx - x0;
    const float v00 = img[y0 * 512 + x0], v01 = img[y0 * 512 + x1];
    const float v10 = img[y1 * 512 + x0], v11 = img[y1 * 512 + x1];
    const float r0 = v00 * (1.f - wy) + v10 * wy;
    const float r1 = v01 * (1.f - wy) + v11 * wy;
    const float t  = r0 * (1.f - wx) + r1 * wx;
    const float p  = bp[idx];
    const float pc  = fminf(fmaxf(p, 1e-12f), 1.0f);
    const float qc  = fminf(fmaxf(1.f - p, 1e-12f), 1.0f);
    const float lp  = fmaxf(__logf(pc), -100.f);
    const float l1p = fmaxf(__logf(qc), -100.f);
    const float bce = -(t * lp + (1.f - t) * l1p);

    __shared__ float sb[4];
    const float s = blk_red<0>(bce, sb);
    if (threadIdx.x == 0) atomicAdd(&ws[WS_BASE_BCE], s);
}

// ---------------- signal phase A: mask detect + per-(b,l) min/max/cnt ----------------
__device__ void sigA_part(int sl, const float* __restrict__ sp,
                          const float* __restrict__ st, const void* __restrict__ mp,
                          float* __restrict__ ws) {
    const int T = 5000;
    const int b = sl / 12, l = sl % 12;
    const float* ps = sp + (size_t)(b * 12 + l) * T;          // (B,12,T)
    const float* ts_base = st + (size_t)b * T * 12 + l;       // (B,T,12)
    const int* mi = (const int*)mp;
    const unsigned char* mb = (const unsigned char*)mp;
    const size_t mbase = (size_t)b * T * 12 + l;

    __shared__ float sb[4];
    __shared__ int s_flag;
    // mask dtype detect: int32 0/1 => bytes at idx%4!=0 are ALL zero.
    if (threadIdx.x == 0) s_flag = 0;
    __syncthreads();
    int f = 0;
    for (int i = threadIdx.x; i < 3072; i += blockDim.x)
        if ((i & 3) && mb[i]) f = 1;
    if (__any(f) && (threadIdx.x & 63) == 0) atomicOr(&s_flag, 1);
    __syncthreads();
    const bool m32 = (s_flag == 0);

    float cnt = 0.f;
    float mnp = __builtin_inff(), mxp = -__builtin_inff();
    float mnt = __builtin_inff(), mxt = -__builtin_inff();
    for (int t = threadIdx.x; t < T; t += blockDim.x) {
        const bool m = m32 ? (mi[mbase + (size_t)t * 12] != 0)
                           : (mb[mbase + (size_t)t * 12] != 0);
        const float p  = ps[t];
        const float tv = ts_base[(size_t)t * 12];
        if (m) {
            cnt += 1.f;
            mnp = fminf(mnp, p);  mxp = fmaxf(mxp, p);
            mnt = fminf(mnt, tv); mxt = fmaxf(mxt, tv);
        }
    }
    cnt = blk_red<0>(cnt, sb);
    mnp = blk_red<1>(mnp, sb); mxp = blk_red<2>(mxp, sb);
    mnt = blk_red<1>(mnt, sb); mxt = blk_red<2>(mxt, sb);

    if (threadIdx.x == 0) {
        float* o = ws + WS_SIGSTATS + sl * 5;
        o[0] = cnt; o[1] = mnp; o[2] = mxp; o[3] = mnt; o[4] = mxt;
        if (sl == 0) ws[WS_MASK_FLAG] = m32 ? 1.0f : 0.0f;
    }
}

// ---------------- mega kernel ----------------
// __launch_bounds__(256,4): 128-VGPR budget so seg's 13 float4 channel loads
// stay simultaneously in flight (R3: compiler chose 40 VGPR -> ~870 GB/s cap).
__global__ __launch_bounds__(256, 4) void mega_kernel(
        const float4* __restrict__ seg_pred, const int4* __restrict__ seg_tgt,
        const float4* __restrict__ grid_pred, const float4* __restrict__ grid_tgt,
        const float* __restrict__ base_pred, const float* __restrict__ base_tgt,
        const float* __restrict__ sig_p, const float* __restrict__ sig_t,
        const void* __restrict__ maskp, float* __restrict__ ws) {
    const int bx = blockIdx.x;
    if (bx < SEG_NB) {
        seg_part(bx, seg_pred, seg_tgt, ws);
    } else if (bx < SEG_NB + GRID_NB) {
        grid_part(bx - SEG_NB, grid_pred, grid_tgt, ws);
    } else if (bx < SEG_NB + GRID_NB + BASE_NB) {
        base_part(bx - SEG_NB - GRID_NB, base_pred, base_tgt, ws);
    } else {
        sigA_part(bx - SEG_NB - GRID_NB - BASE_NB, sig_p, sig_t, maskp, ws);
    }
}

// ---------------- signal phase B + finalize (last-block) ----------------
__global__ __launch_bounds__(256) void sigB_kernel(
        const float* __restrict__ sp, const float* __restrict__ st,
        const void* __restrict__ mp, const float* __restrict__ tp,
        const float* __restrict__ tg, float* __restrict__ ws,
        float* __restrict__ out) {
    const int T = 5000;
    const int sl = blockIdx.x;     // 0..95
    const int b = sl / 12, l = sl % 12;
    const float* ps = sp + (size_t)(b * 12 + l) * T;
    const float* ts_base = st + (size_t)b * T * 12 + l;
    const int* mi = (const int*)mp;
    const unsigned char* mb = (const unsigned char*)mp;
    const size_t mbase = (size_t)b * T * 12 + l;

    __shared__ float sb[4];
    const bool m32 = ws[WS_MASK_FLAG] > 0.5f;
    const float* stats = ws + WS_SIGSTATS + sl * 5;
    const float cnt = stats[0];
    const float mnp = stats[1], mxp = stats[2], mnt = stats[3], mxt = stats[4];

    const float rngp = mxp - mnp, rngt = mxt - mnt;
    const bool okp = (cnt >= 2.f) && (rngp >= 1e-6f);
    const bool okt = (cnt >= 2.f) && (rngt >= 1e-6f);
    const float mnp_s = okp ? mnp : 0.f, rp = okp ? rngp : 1.f;
    const float mnt_s = okt ? mnt : 0.f, rt = okt ? rngt : 1.f;
    const float invp = 2.f / (rp + 1e-8f), invt = 2.f / (rt + 1e-8f);

    float S_p = 0.f, S_t = 0.f, S_pt = 0.f, S_pp = 0.f, S_tt = 0.f, S_abs = 0.f;
    for (int t = threadIdx.x; t < T; t += blockDim.x) {
        const bool m = m32 ? (mi[mbase + (size_t)t * 12] != 0)
                           : (mb[mbase + (size_t)t * 12] != 0);
        const float p  = ps[t];
        const float tv = ts_base[(size_t)t * 12];
        const float pn = (m && okp) ? ((p  - mnp_s) * invp - 1.f) : 0.f;
        const float tn = (m && okt) ? ((tv - mnt_s) * invt - 1.f) : 0.f;
        S_p += pn; S_t += tn;
        S_pt += pn * tn; S_pp += pn * pn; S_tt += tn * tn;
        S_abs += m ? fabsf(pn - tn) : 0.f;
    }
    S_p  = blk_red<0>(S_p, sb);
    S_t  = blk_red<0>(S_t, sb);
    S_pt = blk_red<0>(S_pt, sb);
    S_pp = blk_red<0>(S_pp, sb);
    S_tt = blk_red<0>(S_tt, sb);
    S_abs = blk_red<0>(S_abs, sb);

    __shared__ int s_last;
    if (threadIdx.x == 0) {
        const float cs = fmaxf(cnt, 1.f);
        const float pm = S_p / cs, tm = S_t / cs;
        const float num = S_pt - pm * S_t - tm * S_p + pm * tm * cnt;
        const float psd = sqrtf(fmaxf(S_pp - 2.f * pm * S_p + pm * pm * cnt, 0.f) + 1e-6f);
        const float tsd = sqrtf(fmaxf(S_tt - 2.f * tm * S_t + tm * tm * cnt, 0.f) + 1e-6f);
        float corr = num / (psd * tsd + 1e-6f);
        corr = fminf(fmaxf(corr, -1.f), 1.f);
        const float valid = (cnt >= 10.f) ? 1.f : 0.f;
        atomicAdd(&ws[WS_SIG_ABS],  S_abs);
        atomicAdd(&ws[WS_SIG_CNT],  cnt);
        atomicAdd(&ws[WS_SIG_CORR], corr * valid);
        atomicAdd(&ws[WS_SIG_NV],   valid);
        __threadfence();
        const int old = atomicAdd((int*)(ws + WS_DONE), 1);
        s_last = (old == 95) ? 1 : 0;
    }
    __syncthreads();
    if (!s_last) return;

    // ---- finalize (one block) ----
    __shared__ float s_d, s_nll, s_nv, s_th;
    if (threadIdx.x == 0) { s_d = 0.f; s_nll = 0.f; s_nv = 0.f; s_th = 0.f; }
    __syncthreads();
    const int t = threadIdx.x;
    float d = 0.f, nll = 0.f, nv = 0.f, th = 0.f;
    if (t < 104) {
        const float it = ws[WS_INTER + t], p = ws[WS_PSUM + t], oh = ws[WS_OHCNT + t];
        d = (2.f * it + 1e-7f) / (p + oh + 1e-7f);
    }
    if (t < 8) { nll = ws[WS_SEG_NLL + t]; nv = ws[WS_SEG_VALID + t]; }
    if (t < 48) th = fabsf(tp[t] - tg[t]);
    d = wave_sum(d); nll = wave_sum(nll); nv = wave_sum(nv); th = wave_sum(th);
    if ((t & 63) == 0) {
        atomicAdd(&s_d, d); atomicAdd(&s_nll, nll);
        atomicAdd(&s_nv, nv); atomicAdd(&s_th, th);
    }
    __syncthreads();
    if (t == 0) {
        const float ce = s_nll / fmaxf(s_nv, 1.f);
        const float seg = (ce + (1.f - s_d / 104.f)) * 1.0f;
        const float bce_g = ws[WS_GRID_BCE] / 2097152.f;
        const float gd = 1.f - (2.f * ws[WS_GRID_INTER] + 1e-7f) /
                               (ws[WS_GRID_PSUM] + ws[WS_GRID_TSUM] + 1e-7f);
        const float grid = (bce_g + gd) * 0.5f;
        const float base = (ws[WS_BASE_BCE] / 98304.f) * 0.8f;
        const float theta = (s_th / 48.f) * 0.3f;
        // phase-B sums were written by other blocks' device-scope atomics in
        // THIS dispatch -> read coherently via atomic RMW (+0), not plain loads
        // (per-XCD L2s are not cross-coherent).
        const float sabs = atomicAdd(&ws[WS_SIG_ABS],  0.f);
        const float scnt = atomicAdd(&ws[WS_SIG_CNT],  0.f);
        const float scor = atomicAdd(&ws[WS_SIG_CORR], 0.f);
        const float snv  = atomicAdd(&ws[WS_SIG_NV],   0.f);
        const float mae = sabs / (scnt + 1e-7f);
        const float pear = (snv > 0.f) ? (1.f - scor / fmaxf(snv, 1.f)) : 1.f;
        const float sig = (mae + pear) * 2.0f;
        const float total = seg + grid + base + theta + sig;
        out[0] = seg; out[1] = grid; out[2] = base; out[3] = theta; out[4] = sig;
        out[5] = total;
    }
}

extern "C" void kernel_launch(void* const* d_in, const int* in_sizes, int n_in,
                              void* d_out, int out_size, void* d_ws, size_t ws_size,
                              hipStream_t stream) {
    const float* seg_pred  = (const float*)d_in[0];
    const int*   seg_tgt   = (const int*)d_in[1];
    const float* grid_pred = (const float*)d_in[2];
    const float* grid_tgt  = (const float*)d_in[3];
    const float* base_pred = (const float*)d_in[4];
    const float* base_tgt  = (const float*)d_in[5];
    const float* theta_p   = (const float*)d_in[6];
    const float* theta_g   = (const float*)d_in[7];
    const float* sig_p     = (const float*)d_in[8];
    const float* sig_t     = (const float*)d_in[9];
    const void*  maskp     = d_in[10];
    float* ws  = (float*)d_ws;
    float* out = (float*)d_out;

    hipMemsetAsync(d_ws, 0, WS_FLOATS * sizeof(float), stream);
    mega_kernel<<<TOTAL_NB, 256, 0, stream>>>(
        (const float4*)seg_pred, (const int4*)seg_tgt,
        (const float4*)grid_pred, (const float4*)grid_tgt,
        base_pred, base_tgt, sig_p, sig_t, maskp, ws);
    sigB_kernel<<<96, 256, 0, stream>>>(sig_p, sig_t, maskp, theta_p, theta_g, ws, out);
}

// Round 5
// 288.341 us; speedup vs baseline: 1.4646x; 1.0524x over previous
//
#include <hip/hip_runtime.h>
#include <math.h>

// ---------------- workspace layout (floats) ----------------
#define WS_SEG_NLL    0    // 8 (per b)
#define WS_SEG_VALID  8    // 8
#define WS_INTER      16   // 104 (b*13+c)
#define WS_PSUM       120  // 104
#define WS_OHCNT      224  // 104
#define WS_GRID_BCE   328
#define WS_GRID_INTER 329
#define WS_GRID_PSUM  330
#define WS_GRID_TSUM  331
#define WS_BASE_BCE   332
#define WS_SIG_ABS    333
#define WS_SIG_CNT    334
#define WS_SIG_CORR   335
#define WS_SIG_NV     336
#define WS_MASK_FLAG  337  // 1.0 => mask stored as int32, 0.0 => uint8
#define WS_DONE       338  // int completion counter
#define WS_SIGSTATS   340  // 96*5: cnt,mnp,mxp,mnt,mxt per (b,l)
#define WS_FLOATS     820

// mega-kernel block partition (seg first: longest-running blocks dispatch first)
#define SEG_NB   512
#define GRID_NB  256
#define BASE_NB  384
#define SIGA_NB  96
#define TOTAL_NB (SEG_NB + GRID_NB + BASE_NB + SIGA_NB)

#define AS_GLOBAL const __attribute__((address_space(1))) void*
#define AS_LDS    __attribute__((address_space(3))) void*

__device__ inline float wave_sum(float v) {
    #pragma unroll
    for (int o = 32; o > 0; o >>= 1) v += __shfl_down(v, o, 64);
    return v;
}

// block reduce, result broadcast. OP: 0 sum, 1 min, 2 max. sb: >= nwaves floats
template <int OP>
__device__ inline float blk_red(float v, float* sb) {
    #pragma unroll
    for (int o = 32; o > 0; o >>= 1) {
        float u = __shfl_down(v, o, 64);
        v = (OP == 0) ? (v + u) : ((OP == 1) ? fminf(v, u) : fmaxf(v, u));
    }
    __syncthreads();
    if ((threadIdx.x & 63) == 0) sb[threadIdx.x >> 6] = v;
    __syncthreads();
    const int nw = blockDim.x >> 6;
    float r = sb[0];
    for (int w = 1; w < nw; w++) {
        float u = sb[w];
        r = (OP == 0) ? (r + u) : ((OP == 1) ? fminf(r, u) : fmaxf(r, u));
    }
    return r;
}

// ---------------- seg part: CE(ignore=255) + dice stats ----------------
// global_load_lds staging: each wave fires 7 independent 1KB chunks to LDS
// (fire-and-forget DMA, no VGPR round-trip -> loads actually stay in flight;
// R2-R4's register-resident channel bursts were re-serialized by the
// compiler's pressure-minimizing scheduler and capped at ~870 GB/s).
__device__ void seg_part(int sb_idx, const float* __restrict__ pred,
                         const int* __restrict__ tgt, float* __restrict__ ws) {
    const int b   = sb_idx >> 6;      // batch (64 blocks per batch)
    const int c64 = sb_idx & 63;      // chunk-of-4096-px within batch
    const int HW  = 262144;           // 512*512
    const float* predf = pred + (size_t)b * 13 * HW;
    const int*   tgtb  = tgt + (size_t)b * HW;

    // 26 chunks of pred (13ch x 512px) + 2 chunks of tgt, 256 floats each
    __shared__ alignas(16) float s_tile[28 * 256];
    int* s_tgt_i = (int*)&s_tile[26 * 256];
    __shared__ float s_inter[13];
    __shared__ float s_psum[13];
    __shared__ int   s_cnt[13];
    __shared__ float s_nll;
    __shared__ float s_nval;
    if (threadIdx.x < 13) { s_inter[threadIdx.x] = 0.f; s_psum[threadIdx.x] = 0.f; s_cnt[threadIdx.x] = 0; }
    if (threadIdx.x == 13) s_nll = 0.f;
    if (threadIdx.x == 14) s_nval = 0.f;

    const int lane = threadIdx.x & 63;
    const int wv   = threadIdx.x >> 6;

    float psum[13];
    #pragma unroll
    for (int c = 0; c < 13; c++) psum[c] = 0.f;
    float nll = 0.f, nval = 0.f;

    #pragma unroll 1
    for (int tile = 0; tile < 8; tile++) {
        const int px0 = c64 * 4096 + tile * 512;
        // issue this wave's 7 chunks, all outstanding
        #pragma unroll
        for (int i = 0; i < 7; i++) {
            const int k = wv * 7 + i;
            const float* g;
            if (k < 26) g = predf + (size_t)(k >> 1) * HW + px0 + (k & 1) * 256;
            else        g = (const float*)(tgtb + px0 + (k - 26) * 256);
            g += lane * 4;
            __builtin_amdgcn_global_load_lds((AS_GLOBAL)g,
                                             (AS_LDS)&s_tile[k * 256], 16, 0, 0);
        }
        __syncthreads();   // vmcnt(0) drain + barrier: tile fully in LDS

        #pragma unroll
        for (int kp = 0; kp < 2; kp++) {
            const int p = threadIdx.x + kp * 256;
            const int t = s_tgt_i[p];
            float x[13];
            #pragma unroll
            for (int c = 0; c < 13; c++) x[c] = s_tile[c * 512 + p];
            float m = x[0];
            #pragma unroll
            for (int c = 1; c < 13; c++) m = fmaxf(m, x[c]);
            float xt = x[0];
            #pragma unroll
            for (int c = 1; c < 13; c++) xt = (c == t) ? x[c] : xt;
            float se = 0.f;
            #pragma unroll
            for (int c = 0; c < 13; c++) { x[c] = __expf(x[c] - m); se += x[c]; }
            const float inv = __builtin_amdgcn_rcpf(se);
            #pragma unroll
            for (int c = 0; c < 13; c++) psum[c] += x[c] * inv;
            if ((unsigned)t < 13u) {
                atomicAdd(&s_inter[t], __expf(xt - m) * inv);
                atomicAdd(&s_cnt[t], 1);
                nll  += m + __logf(se) - xt;
                nval += 1.f;
            }
        }
        if (tile < 7) __syncthreads();   // protect s_tile before next DMA
    }

    const bool lane0 = (lane == 0);
    #pragma unroll
    for (int c = 0; c < 13; c++) {
        float a = wave_sum(psum[c]);
        if (lane0) atomicAdd(&s_psum[c], a);
    }
    { float a = wave_sum(nll);  if (lane0) atomicAdd(&s_nll, a); }
    { float a = wave_sum(nval); if (lane0) atomicAdd(&s_nval, a); }
    __syncthreads();
    if (threadIdx.x < 13) {
        atomicAdd(&ws[WS_PSUM  + b * 13 + threadIdx.x], s_psum[threadIdx.x]);
        atomicAdd(&ws[WS_INTER + b * 13 + threadIdx.x], s_inter[threadIdx.x]);
        atomicAdd(&ws[WS_OHCNT + b * 13 + threadIdx.x], (float)s_cnt[threadIdx.x]);
    }
    if (threadIdx.x == 64) atomicAdd(&ws[WS_SEG_NLL + b],   s_nll);
    if (threadIdx.x == 65) atomicAdd(&ws[WS_SEG_VALID + b], s_nval);
}

// ---------------- grid part: BCE + dice scalars ----------------
__device__ void grid_part(int gb, const float4* __restrict__ gp,
                          const float4* __restrict__ gt, float* __restrict__ ws) {
    const int N4 = 2097152 / 4;
    float bce = 0.f, inter = 0.f, ps = 0.f, ts = 0.f;
    const int stride = GRID_NB * 256;
    for (int i = gb * 256 + threadIdx.x; i < N4; i += stride) {
        const float4 p4 = gp[i];
        const float4 t4 = gt[i];
        const float pa[4] = {p4.x, p4.y, p4.z, p4.w};
        const float ta[4] = {t4.x, t4.y, t4.z, t4.w};
        #pragma unroll
        for (int k = 0; k < 4; k++) {
            const float p = pa[k], t = ta[k];
            const float pc  = fminf(fmaxf(p, 1e-12f), 1.0f);
            const float qc  = fminf(fmaxf(1.f - p, 1e-12f), 1.0f);
            const float lp  = fmaxf(__logf(pc), -100.f);
            const float l1p = fmaxf(__logf(qc), -100.f);
            bce  -= t * lp + (1.f - t) * l1p;
            inter += p * t;
            ps += p;
            ts += t;
        }
    }
    __shared__ float s4[4];
    if (threadIdx.x < 4) s4[threadIdx.x] = 0.f;
    __syncthreads();
    const bool lane0 = (threadIdx.x & 63) == 0;
    { float a = wave_sum(bce);   if (lane0) atomicAdd(&s4[0], a); }
    { float a = wave_sum(inter); if (lane0) atomicAdd(&s4[1], a); }
    { float a = wave_sum(ps);    if (lane0) atomicAdd(&s4[2], a); }
    { float a = wave_sum(ts);    if (lane0) atomicAdd(&s4[3], a); }
    __syncthreads();
    if (threadIdx.x == 0) {
        atomicAdd(&ws[WS_GRID_BCE],   s4[0]);
        atomicAdd(&ws[WS_GRID_INTER], s4[1]);
        atomicAdd(&ws[WS_GRID_PSUM],  s4[2]);
        atomicAdd(&ws[WS_GRID_TSUM],  s4[3]);
    }
}

// ---------------- baseline part: bilinear(align_corners) gather + BCE ----------------
__device__ void base_part(int bb, const float* __restrict__ bp,
                          const float* __restrict__ bt, float* __restrict__ ws) {
    const int idx = bb * 256 + threadIdx.x;   // 0..98303
    const int w  = idx & 31;
    const int h  = (idx >> 5) & 31;
    const int bc = idx >> 10;                 // b*12 + c
    const float* img = bt + (size_t)bc * 262144;
    const float step = 511.0f / 31.0f;
    const float yy = h * step, xx = w * step;
    int y0 = (int)floorf(yy); int y1 = min(y0 + 1, 511); const float wy = yy - y0;
    int x0 = (int)floorf(xx); int x1 = min(x0 + 1, 511); const float wx = xx - x0;
    const float v00 = img[y0 * 512 + x0], v01 = img[y0 * 512 + x1];
    const float v10 = img[y1 * 512 + x0], v11 = img[y1 * 512 + x1];
    const float r0 = v00 * (1.f - wy) + v10 * wy;
    const float r1 = v01 * (1.f - wy) + v11 * wy;
    const float t  = r0 * (1.f - wx) + r1 * wx;
    const float p  = bp[idx];
    const float pc  = fminf(fmaxf(p, 1e-12f), 1.0f);
    const float qc  = fminf(fmaxf(1.f - p, 1e-12f), 1.0f);
    const float lp  = fmaxf(__logf(pc), -100.f);
    const float l1p = fmaxf(__logf(qc), -100.f);
    const float bce = -(t * lp + (1.f - t) * l1p);

    __shared__ float sb[4];
    const float s = blk_red<0>(bce, sb);
    if (threadIdx.x == 0) atomicAdd(&ws[WS_BASE_BCE], s);
}

// ---------------- signal phase A: mask detect + per-(b,l) min/max/cnt ----------------
__device__ void sigA_part(int sl, const float* __restrict__ sp,
                          const float* __restrict__ st, const void* __restrict__ mp,
                          float* __restrict__ ws) {
    const int T = 5000;
    const int b = sl / 12, l = sl % 12;
    const float* ps = sp + (size_t)(b * 12 + l) * T;          // (B,12,T)
    const float* ts_base = st + (size_t)b * T * 12 + l;       // (B,T,12)
    const int* mi = (const int*)mp;
    const unsigned char* mb = (const unsigned char*)mp;
    const size_t mbase = (size_t)b * T * 12 + l;

    __shared__ float sb[4];
    __shared__ int s_flag;
    // mask dtype detect: int32 0/1 => bytes at idx%4!=0 are ALL zero.
    if (threadIdx.x == 0) s_flag = 0;
    __syncthreads();
    int f = 0;
    for (int i = threadIdx.x; i < 3072; i += blockDim.x)
        if ((i & 3) && mb[i]) f = 1;
    if (__any(f) && (threadIdx.x & 63) == 0) atomicOr(&s_flag, 1);
    __syncthreads();
    const bool m32 = (s_flag == 0);

    float cnt = 0.f;
    float mnp = __builtin_inff(), mxp = -__builtin_inff();
    float mnt = __builtin_inff(), mxt = -__builtin_inff();
    for (int t = threadIdx.x; t < T; t += blockDim.x) {
        const bool m = m32 ? (mi[mbase + (size_t)t * 12] != 0)
                           : (mb[mbase + (size_t)t * 12] != 0);
        const float p  = ps[t];
        const float tv = ts_base[(size_t)t * 12];
        if (m) {
            cnt += 1.f;
            mnp = fminf(mnp, p);  mxp = fmaxf(mxp, p);
            mnt = fminf(mnt, tv); mxt = fmaxf(mxt, tv);
        }
    }
    cnt = blk_red<0>(cnt, sb);
    mnp = blk_red<1>(mnp, sb); mxp = blk_red<2>(mxp, sb);
    mnt = blk_red<1>(mnt, sb); mxt = blk_red<2>(mxt, sb);

    if (threadIdx.x == 0) {
        float* o = ws + WS_SIGSTATS + sl * 5;
        o[0] = cnt; o[1] = mnp; o[2] = mxp; o[3] = mnt; o[4] = mxt;
        if (sl == 0) ws[WS_MASK_FLAG] = m32 ? 1.0f : 0.0f;
    }
}

// ---------------- mega kernel ----------------
__global__ __launch_bounds__(256) void mega_kernel(
        const float* __restrict__ seg_pred, const int* __restrict__ seg_tgt,
        const float4* __restrict__ grid_pred, const float4* __restrict__ grid_tgt,
        const float* __restrict__ base_pred, const float* __restrict__ base_tgt,
        const float* __restrict__ sig_p, const float* __restrict__ sig_t,
        const void* __restrict__ maskp, float* __restrict__ ws) {
    const int bx = blockIdx.x;
    if (bx < SEG_NB) {
        seg_part(bx, seg_pred, seg_tgt, ws);
    } else if (bx < SEG_NB + GRID_NB) {
        grid_part(bx - SEG_NB, grid_pred, grid_tgt, ws);
    } else if (bx < SEG_NB + GRID_NB + BASE_NB) {
        base_part(bx - SEG_NB - GRID_NB, base_pred, base_tgt, ws);
    } else {
        sigA_part(bx - SEG_NB - GRID_NB - BASE_NB, sig_p, sig_t, maskp, ws);
    }
}

// ---------------- signal phase B + finalize (last-block) ----------------
__global__ __launch_bounds__(256) void sigB_kernel(
        const float* __restrict__ sp, const float* __restrict__ st,
        const void* __restrict__ mp, const float* __restrict__ tp,
        const float* __restrict__ tg, float* __restrict__ ws,
        float* __restrict__ out) {
    const int T = 5000;
    const int sl = blockIdx.x;     // 0..95
    const int b = sl / 12, l = sl % 12;
    const float* ps = sp + (size_t)(b * 12 + l) * T;
    const float* ts_base = st + (size_t)b * T * 12 + l;
    const int* mi = (const int*)mp;
    const unsigned char* mb = (const unsigned char*)mp;
    const size_t mbase = (size_t)b * T * 12 + l;

    __shared__ float sb[4];
    const bool m32 = ws[WS_MASK_FLAG] > 0.5f;
    const float* stats = ws + WS_SIGSTATS + sl * 5;
    const float cnt = stats[0];
    const float mnp = stats[1], mxp = stats[2], mnt = stats[3], mxt = stats[4];

    const float rngp = mxp - mnp, rngt = mxt - mnt;
    const bool okp = (cnt >= 2.f) && (rngp >= 1e-6f);
    const bool okt = (cnt >= 2.f) && (rngt >= 1e-6f);
    const float mnp_s = okp ? mnp : 0.f, rp = okp ? rngp : 1.f;
    const float mnt_s = okt ? mnt : 0.f, rt = okt ? rngt : 1.f;
    const float invp = 2.f / (rp + 1e-8f), invt = 2.f / (rt + 1e-8f);

    float S_p = 0.f, S_t = 0.f, S_pt = 0.f, S_pp = 0.f, S_tt = 0.f, S_abs = 0.f;
    for (int t = threadIdx.x; t < T; t += blockDim.x) {
        const bool m = m32 ? (mi[mbase + (size_t)t * 12] != 0)
                           : (mb[mbase + (size_t)t * 12] != 0);
        const float p  = ps[t];
        const float tv = ts_base[(size_t)t * 12];
        const float pn = (m && okp) ? ((p  - mnp_s) * invp - 1.f) : 0.f;
        const float tn = (m && okt) ? ((tv - mnt_s) * invt - 1.f) : 0.f;
        S_p += pn; S_t += tn;
        S_pt += pn * tn; S_pp += pn * pn; S_tt += tn * tn;
        S_abs += m ? fabsf(pn - tn) : 0.f;
    }
    S_p  = blk_red<0>(S_p, sb);
    S_t  = blk_red<0>(S_t, sb);
    S_pt = blk_red<0>(S_pt, sb);
    S_pp = blk_red<0>(S_pp, sb);
    S_tt = blk_red<0>(S_tt, sb);
    S_abs = blk_red<0>(S_abs, sb);

    __shared__ int s_last;
    if (threadIdx.x == 0) {
        const float cs = fmaxf(cnt, 1.f);
        const float pm = S_p / cs, tm = S_t / cs;
        const float num = S_pt - pm * S_t - tm * S_p + pm * tm * cnt;
        const float psd = sqrtf(fmaxf(S_pp - 2.f * pm * S_p + pm * pm * cnt, 0.f) + 1e-6f);
        const float tsd = sqrtf(fmaxf(S_tt - 2.f * tm * S_t + tm * tm * cnt, 0.f) + 1e-6f);
        float corr = num / (psd * tsd + 1e-6f);
        corr = fminf(fmaxf(corr, -1.f), 1.f);
        const float valid = (cnt >= 10.f) ? 1.f : 0.f;
        atomicAdd(&ws[WS_SIG_ABS],  S_abs);
        atomicAdd(&ws[WS_SIG_CNT],  cnt);
        atomicAdd(&ws[WS_SIG_CORR], corr * valid);
        atomicAdd(&ws[WS_SIG_NV],   valid);
        __threadfence();
        const int old = atomicAdd((int*)(ws + WS_DONE), 1);
        s_last = (old == 95) ? 1 : 0;
    }
    __syncthreads();
    if (!s_last) return;

    // ---- finalize (one block) ----
    __shared__ float s_d, s_nll, s_nv, s_th;
    if (threadIdx.x == 0) { s_d = 0.f; s_nll = 0.f; s_nv = 0.f; s_th = 0.f; }
    __syncthreads();
    const int t = threadIdx.x;
    float d = 0.f, nll = 0.f, nv = 0.f, th = 0.f;
    if (t < 104) {
        const float it = ws[WS_INTER + t], p = ws[WS_PSUM + t], oh = ws[WS_OHCNT + t];
        d = (2.f * it + 1e-7f) / (p + oh + 1e-7f);
    }
    if (t < 8) { nll = ws[WS_SEG_NLL + t]; nv = ws[WS_SEG_VALID + t]; }
    if (t < 48) th = fabsf(tp[t] - tg[t]);
    d = wave_sum(d); nll = wave_sum(nll); nv = wave_sum(nv); th = wave_sum(th);
    if ((t & 63) == 0) {
        atomicAdd(&s_d, d); atomicAdd(&s_nll, nll);
        atomicAdd(&s_nv, nv); atomicAdd(&s_th, th);
    }
    __syncthreads();
    if (t == 0) {
        const float ce = s_nll / fmaxf(s_nv, 1.f);
        const float seg = (ce + (1.f - s_d / 104.f)) * 1.0f;
        const float bce_g = ws[WS_GRID_BCE] / 2097152.f;
        const float gd = 1.f - (2.f * ws[WS_GRID_INTER] + 1e-7f) /
                               (ws[WS_GRID_PSUM] + ws[WS_GRID_TSUM] + 1e-7f);
        const float grid = (bce_g + gd) * 0.5f;
        const float base = (ws[WS_BASE_BCE] / 98304.f) * 0.8f;
        const float theta = (s_th / 48.f) * 0.3f;
        // phase-B sums were written by other blocks' device-scope atomics in
        // THIS dispatch -> read coherently via atomic RMW (+0), not plain loads
        // (per-XCD L2s are not cross-coherent).
        const float sabs = atomicAdd(&ws[WS_SIG_ABS],  0.f);
        const float scnt = atomicAdd(&ws[WS_SIG_CNT],  0.f);
        const float scor = atomicAdd(&ws[WS_SIG_CORR], 0.f);
        const float snv  = atomicAdd(&ws[WS_SIG_NV],   0.f);
        const float mae = sabs / (scnt + 1e-7f);
        const float pear = (snv > 0.f) ? (1.f - scor / fmaxf(snv, 1.f)) : 1.f;
        const float sig = (mae + pear) * 2.0f;
        const float total = seg + grid + base + theta + sig;
        out[0] = seg; out[1] = grid; out[2] = base; out[3] = theta; out[4] = sig;
        out[5] = total;
    }
}

extern "C" void kernel_launch(void* const* d_in, const int* in_sizes, int n_in,
                              void* d_out, int out_size, void* d_ws, size_t ws_size,
                              hipStream_t stream) {
    const float* seg_pred  = (const float*)d_in[0];
    const int*   seg_tgt   = (const int*)d_in[1];
    const float* grid_pred = (const float*)d_in[2];
    const float* grid_tgt  = (const float*)d_in[3];
    const float* base_pred = (const float*)d_in[4];
    const float* base_tgt  = (const float*)d_in[5];
    const float* theta_p   = (const float*)d_in[6];
    const float* theta_g   = (const float*)d_in[7];
    const float* sig_p     = (const float*)d_in[8];
    const float* sig_t     = (const float*)d_in[9];
    const void*  maskp     = d_in[10];
    float* ws  = (float*)d_ws;
    float* out = (float*)d_out;

    hipMemsetAsync(d_ws, 0, WS_FLOATS * sizeof(float), stream);
    mega_kernel<<<TOTAL_NB, 256, 0, stream>>>(
        seg_pred, seg_tgt,
        (const float4*)grid_pred, (const float4*)grid_tgt,
        base_pred, base_tgt, sig_p, sig_t, maskp, ws);
    sigB_kernel<<<96, 256, 0, stream>>>(sig_p, sig_t, maskp, theta_p, theta_g, ws, out);
}